// Round 1
// baseline (150.432 us; speedup 1.0000x reference)
//
#include <hip/hip_runtime.h>
#include <hip/hip_bf16.h>

#define NN 4096
#define IN_DIM 512
#define OUT_DIM 256
#define NH 4
#define HD 64
#define NEG_SLOPE 0.2f
#define LN_EPS 1e-5f

typedef __attribute__((ext_vector_type(8))) short short8;
typedef __attribute__((ext_vector_type(4))) float f32x4;
typedef unsigned short u16;
typedef unsigned int u32;

// ---------------------------------------------------------------------------
// K1: Wx[h] = x @ W[h]  (f32 accum). Epilogue: WxT bf16 [h][d][j], s_src, d_dst.
// grid 512 (h*128 + rowtile), block 256. Tile: 32 rows x 64 cols, K-chunks of 32.
// ---------------------------------------------------------------------------
__global__ __launch_bounds__(256) void k1_proj(
    const float* __restrict__ x, const float* __restrict__ W,
    const float* __restrict__ a,
    u16* __restrict__ WxT,
    float* __restrict__ s_src,
    float* __restrict__ d_dst)
{
  const int b = blockIdx.x;
  const int h = b >> 7;
  const int i0 = (b & 127) * 32;
  const int t = threadIdx.x;
  const int lane = t & 63;   // output col d
  const int rg = t >> 6;     // wave id -> rows rg*8 .. rg*8+7

  __shared__ float xT[32][34];   // [kk][row], pad 34 (8B-aligned rows, ~2-way banks)
  __shared__ float Wl[32][64];   // [kk][d]

  float acc[8];
#pragma unroll
  for (int r = 0; r < 8; ++r) acc[r] = 0.f;

  for (int k0 = 0; k0 < IN_DIM; k0 += 32) {
    __syncthreads();
    {
      const int r = t >> 3;
      const int kg = t & 7;
      const float4 xv = *reinterpret_cast<const float4*>(
          x + (size_t)(i0 + r) * IN_DIM + k0 + kg * 4);
      xT[kg * 4 + 0][r] = xv.x;
      xT[kg * 4 + 1][r] = xv.y;
      xT[kg * 4 + 2][r] = xv.z;
      xT[kg * 4 + 3][r] = xv.w;
    }
    {
      const int kk0 = t >> 6;
#pragma unroll
      for (int i2 = 0; i2 < 8; ++i2) {
        const int kk = kk0 * 8 + i2;
        Wl[kk][lane] = W[((size_t)h * IN_DIM + k0 + kk) * HD + lane];
      }
    }
    __syncthreads();
#pragma unroll 4
    for (int kk = 0; kk < 32; ++kk) {
      const float w = Wl[kk][lane];
      const float2* xp = reinterpret_cast<const float2*>(&xT[kk][rg * 8]);
      const float2 x01 = xp[0], x23 = xp[1], x45 = xp[2], x67 = xp[3];
      acc[0] = fmaf(x01.x, w, acc[0]);
      acc[1] = fmaf(x01.y, w, acc[1]);
      acc[2] = fmaf(x23.x, w, acc[2]);
      acc[3] = fmaf(x23.y, w, acc[3]);
      acc[4] = fmaf(x45.x, w, acc[4]);
      acc[5] = fmaf(x45.y, w, acc[5]);
      acc[6] = fmaf(x67.x, w, acc[6]);
      acc[7] = fmaf(x67.y, w, acc[7]);
    }
  }

  // ---- epilogue: bf16 transpose-store + attention scalars ----
  const float asw = a[(size_t)h * 2 * HD + lane];        // a_src weight for dim d
  const float adw = a[(size_t)h * 2 * HD + HD + lane];   // a_dst weight for dim d

  u16 us[8];
#pragma unroll
  for (int r = 0; r < 8; ++r) {
    __hip_bfloat16 bv = __float2bfloat16(acc[r]);
    us[r] = *reinterpret_cast<const u16*>(&bv);
  }
  uint4 pk;
  pk.x = (u32)us[0] | ((u32)us[1] << 16);
  pk.y = (u32)us[2] | ((u32)us[3] << 16);
  pk.z = (u32)us[4] | ((u32)us[5] << 16);
  pk.w = (u32)us[6] | ((u32)us[7] << 16);
  *reinterpret_cast<uint4*>(WxT + (size_t)(h * HD + lane) * NN + i0 + rg * 8) = pk;

#pragma unroll
  for (int r = 0; r < 8; ++r) {
    float sv = acc[r] * asw;
    float dv = acc[r] * adw;
#pragma unroll
    for (int mm = 32; mm >= 1; mm >>= 1) {
      sv += __shfl_xor(sv, mm);
      dv += __shfl_xor(dv, mm);
    }
    if (lane == 0) {
      const int i = i0 + rg * 8 + r;
      s_src[(size_t)h * NN + i] = sv;
      d_dst[(size_t)h * NN + i] = dv;
    }
  }
}

// ---------------------------------------------------------------------------
// K2: maxd[h] = max_j d_dst[h][j]  (upper bound for softmax stabilization)
// ---------------------------------------------------------------------------
__global__ __launch_bounds__(256) void k2_maxd(
    const float* __restrict__ d_dst, float* __restrict__ maxd)
{
  __shared__ float red[4];
  const int t = threadIdx.x;
  for (int h = 0; h < NH; ++h) {
    float mx = -3.4e38f;
    for (int idx = t; idx < NN; idx += 256) mx = fmaxf(mx, d_dst[(size_t)h * NN + idx]);
#pragma unroll
    for (int mm = 32; mm >= 1; mm >>= 1) mx = fmaxf(mx, __shfl_xor(mx, mm));
    if ((t & 63) == 0) red[t >> 6] = mx;
    __syncthreads();
    if (t == 0) maxd[h] = fmaxf(fmaxf(red[0], red[1]), fmaxf(red[2], red[3]));
    __syncthreads();
  }
}

// ---------------------------------------------------------------------------
// K3: masked rank-1-score softmax + PV (bf16 MFMA) + ELU + LayerNorm, fused.
// grid 256 (16-row tiles), block 1024 = 16 waves: wave = (h = wv&3, jq = wv>>2).
// Each wave: j in [jq*1024, jq*1024+1024), 32 K-steps of 32.
// A-frag (p) built in-register: A row = lane&15, k-slice = (lane>>4)*8 + e.
// B-frag from WxT[h][d][j] (d = dt*16 + lane&15): contiguous 16B along j.
// Upper-bound max => partial softmax sums merge by plain addition across jq.
// ---------------------------------------------------------------------------
__global__ __launch_bounds__(1024) void k3_attn(
    const int* __restrict__ adj,
    const u16* __restrict__ WxT,
    const float* __restrict__ s_src, const float* __restrict__ d_dst,
    const float* __restrict__ maxd,
    const float* __restrict__ gamma, const float* __restrict__ beta,
    float* __restrict__ out)
{
  const int i0 = blockIdx.x * 16;
  const int t = threadIdx.x;
  const int wv = t >> 6;
  const int lane = t & 63;
  const int h = wv & 3;
  const int jq = wv >> 2;
  const int rloc = lane & 15;
  const int g = lane >> 4;
  const int i = i0 + rloc;

  __shared__ float lout[16][OUT_DIM];   // 16 KiB accumulation buffer
  __shared__ float lsum[NH][16];

  const float si = s_src[(size_t)h * NN + i];
  const float e0 = si + maxd[h];
  const float m = fmaxf(e0, NEG_SLOPE * e0);   // leaky is monotone => valid ub

  f32x4 acc[4] = {};
  float sump = 0.f;

  const size_t adj_row = (size_t)i * NN;

  for (int step = 0; step < 32; ++step) {
    const int jb = jq * 1024 + step * 32 + g * 8;
    const int4 a0 = *reinterpret_cast<const int4*>(adj + adj_row + jb);
    const int4 a1 = *reinterpret_cast<const int4*>(adj + adj_row + jb + 4);
    const float4 dv0 = *reinterpret_cast<const float4*>(d_dst + (size_t)h * NN + jb);
    const float4 dv1 = *reinterpret_cast<const float4*>(d_dst + (size_t)h * NN + jb + 4);
    const int am[8] = {a0.x, a0.y, a0.z, a0.w, a1.x, a1.y, a1.z, a1.w};
    const float dvv[8] = {dv0.x, dv0.y, dv0.z, dv0.w, dv1.x, dv1.y, dv1.z, dv1.w};
    short8 af;
#pragma unroll
    for (int e = 0; e < 8; ++e) {
      const float ev = si + dvv[e];
      const float lv = fmaxf(ev, NEG_SLOPE * ev);
      const bool on = (am[e] > 0) || (i == jb + e);
      const float pv = on ? __expf(lv - m) : 0.f;
      sump += pv;
      __hip_bfloat16 bb = __float2bfloat16(pv);
      af[e] = *reinterpret_cast<const short*>(&bb);
    }
#pragma unroll
    for (int dt = 0; dt < 4; ++dt) {
      const int d = dt * 16 + rloc;
      const short8 bfr = *reinterpret_cast<const short8*>(
          WxT + (size_t)(h * HD + d) * NN + jb);
      acc[dt] = __builtin_amdgcn_mfma_f32_16x16x32_bf16(af, bfr, acc[dt], 0, 0, 0);
    }
  }

  // full row-sum: combine the 4 k-groups (lanes xor 16, 32)
  sump += __shfl_xor(sump, 16);
  sump += __shfl_xor(sump, 32);

  // merge partial results across jq (linear since same m): 4 ordered passes
  for (int pass = 0; pass < 4; ++pass) {
    if (jq == pass) {
      if (pass == 0) {
#pragma unroll
        for (int dt = 0; dt < 4; ++dt)
#pragma unroll
          for (int q = 0; q < 4; ++q)
            lout[g * 4 + q][h * HD + dt * 16 + rloc] = acc[dt][q];
        if (lane < 16) lsum[h][lane] = sump;
      } else {
#pragma unroll
        for (int dt = 0; dt < 4; ++dt)
#pragma unroll
          for (int q = 0; q < 4; ++q)
            lout[g * 4 + q][h * HD + dt * 16 + rloc] += acc[dt][q];
        if (lane < 16) lsum[h][lane] += sump;
      }
    }
    __syncthreads();
  }

  // normalize + ELU (first 256 threads own one output column each)
  if (t < OUT_DIM) {
    const int c = t;
    const int hh = c >> 6;
#pragma unroll
    for (int r = 0; r < 16; ++r) {
      float v = lout[r][c] / lsum[hh][r];
      v = (v > 0.f) ? v : expm1f(v);
      lout[r][c] = v;
    }
  }
  __syncthreads();

  // LayerNorm: wave wv handles row wv (lanes own 4 cols each)
  {
    const int r = wv;
    float xv[4];
    float sum = 0.f, sq = 0.f;
#pragma unroll
    for (int q = 0; q < 4; ++q) {
      xv[q] = lout[r][q * 64 + lane];
      sum += xv[q];
      sq += xv[q] * xv[q];
    }
#pragma unroll
    for (int mm = 32; mm >= 1; mm >>= 1) {
      sum += __shfl_xor(sum, mm);
      sq += __shfl_xor(sq, mm);
    }
    const float mu = sum * (1.f / OUT_DIM);
    const float var = sq * (1.f / OUT_DIM) - mu * mu;
    const float rs = rsqrtf(var + LN_EPS);
#pragma unroll
    for (int q = 0; q < 4; ++q) {
      const int c = q * 64 + lane;
      out[(size_t)(i0 + r) * OUT_DIM + c] = (xv[q] - mu) * rs * gamma[c] + beta[c];
    }
  }
}

extern "C" void kernel_launch(void* const* d_in, const int* in_sizes, int n_in,
                              void* d_out, int out_size, void* d_ws, size_t ws_size,
                              hipStream_t stream) {
  const float* x = (const float*)d_in[0];
  const int* adj = (const int*)d_in[1];
  const float* W = (const float*)d_in[2];
  const float* a = (const float*)d_in[3];
  const float* gamma = (const float*)d_in[4];
  const float* beta = (const float*)d_in[5];
  float* out = (float*)d_out;

  char* ws = (char*)d_ws;
  u16* WxT = (u16*)ws;                                          // 2 MiB
  float* s_src = (float*)(ws + (size_t)NH * HD * NN * 2);       // 64 KiB
  float* d_dst = s_src + (size_t)NH * NN;                       // 64 KiB
  float* maxd = d_dst + (size_t)NH * NN;                        // 16 B

  k1_proj<<<dim3(512), dim3(256), 0, stream>>>(x, W, a, WxT, s_src, d_dst);
  k2_maxd<<<dim3(1), dim3(256), 0, stream>>>(d_dst, maxd);
  k3_attn<<<dim3(256), dim3(1024), 0, stream>>>(adj, WxT, s_src, d_dst, maxd,
                                                gamma, beta, out);
}

// Round 3
// 148.674 us; speedup vs baseline: 1.0118x; 1.0118x over previous
//
#include <hip/hip_runtime.h>
#include <hip/hip_bf16.h>

#define NN 4096
#define IN_DIM 512
#define OUT_DIM 256
#define NH 4
#define HD 64
#define NEG_SLOPE 0.2f
#define LN_EPS 1e-5f

typedef __attribute__((ext_vector_type(8))) short short8;
typedef __attribute__((ext_vector_type(4))) float f32x4;
typedef unsigned short u16;
typedef unsigned int u32;
typedef unsigned long long u64;
typedef unsigned char u8;

// ---------------------------------------------------------------------------
// K0: pack (adj>0)|I into a bitmask [NN][NN/8 bytes], self-loops folded in.
// grid 4096 (one row/block), block 1024. Coalesced 4B/lane reads, ballot pack.
// ---------------------------------------------------------------------------
__global__ __launch_bounds__(1024) void k0_pack(
    const int* __restrict__ adj, u64* __restrict__ mask)
{
  const int row = blockIdx.x;
  const int t = threadIdx.x;
  const int wv = t >> 6;
  const int lane = t & 63;
#pragma unroll
  for (int it = 0; it < 4; ++it) {
    const int j = it * 1024 + t;
    const int v = adj[(size_t)row * NN + j];
    const bool on = (v > 0) || (row == j);
    const u64 bm = __ballot(on);
    if (lane == 0) mask[(size_t)row * 64 + it * 16 + wv] = bm;
  }
}

// ---------------------------------------------------------------------------
// K1: Wx[h] = x @ W[h]  (f32 accum). Epilogue: WxT bf16 [h][d][j], s_src, d_dst.
// grid 512 (h*128 + rowtile), block 256. Tile: 32 rows x 64 cols, K-chunks of 32.
// ---------------------------------------------------------------------------
__global__ __launch_bounds__(256) void k1_proj(
    const float* __restrict__ x, const float* __restrict__ W,
    const float* __restrict__ a,
    u16* __restrict__ WxT,
    float* __restrict__ s_src,
    float* __restrict__ d_dst)
{
  const int b = blockIdx.x;
  const int h = b >> 7;
  const int i0 = (b & 127) * 32;
  const int t = threadIdx.x;
  const int lane = t & 63;   // output col d
  const int rg = t >> 6;     // wave id -> rows rg*8 .. rg*8+7

  __shared__ float xT[32][34];   // [kk][row]
  __shared__ float Wl[32][64];   // [kk][d]

  float acc[8];
#pragma unroll
  for (int r = 0; r < 8; ++r) acc[r] = 0.f;

  for (int k0 = 0; k0 < IN_DIM; k0 += 32) {
    __syncthreads();
    {
      const int r = t >> 3;
      const int kg = t & 7;
      const float4 xv = *reinterpret_cast<const float4*>(
          x + (size_t)(i0 + r) * IN_DIM + k0 + kg * 4);
      xT[kg * 4 + 0][r] = xv.x;
      xT[kg * 4 + 1][r] = xv.y;
      xT[kg * 4 + 2][r] = xv.z;
      xT[kg * 4 + 3][r] = xv.w;
    }
    {
      const int kk0 = t >> 6;
#pragma unroll
      for (int i2 = 0; i2 < 8; ++i2) {
        const int kk = kk0 * 8 + i2;
        Wl[kk][lane] = W[((size_t)h * IN_DIM + k0 + kk) * HD + lane];
      }
    }
    __syncthreads();
#pragma unroll 4
    for (int kk = 0; kk < 32; ++kk) {
      const float w = Wl[kk][lane];
      const float2* xp = reinterpret_cast<const float2*>(&xT[kk][rg * 8]);
      const float2 x01 = xp[0], x23 = xp[1], x45 = xp[2], x67 = xp[3];
      acc[0] = fmaf(x01.x, w, acc[0]);
      acc[1] = fmaf(x01.y, w, acc[1]);
      acc[2] = fmaf(x23.x, w, acc[2]);
      acc[3] = fmaf(x23.y, w, acc[3]);
      acc[4] = fmaf(x45.x, w, acc[4]);
      acc[5] = fmaf(x45.y, w, acc[5]);
      acc[6] = fmaf(x67.x, w, acc[6]);
      acc[7] = fmaf(x67.y, w, acc[7]);
    }
  }

  // ---- epilogue: bf16 transpose-store + attention scalars ----
  const float asw = a[(size_t)h * 2 * HD + lane];
  const float adw = a[(size_t)h * 2 * HD + HD + lane];

  u16 us[8];
#pragma unroll
  for (int r = 0; r < 8; ++r) {
    __hip_bfloat16 bv = __float2bfloat16(acc[r]);
    us[r] = *reinterpret_cast<const u16*>(&bv);
  }
  uint4 pk;
  pk.x = (u32)us[0] | ((u32)us[1] << 16);
  pk.y = (u32)us[2] | ((u32)us[3] << 16);
  pk.z = (u32)us[4] | ((u32)us[5] << 16);
  pk.w = (u32)us[6] | ((u32)us[7] << 16);
  *reinterpret_cast<uint4*>(WxT + (size_t)(h * HD + lane) * NN + i0 + rg * 8) = pk;

#pragma unroll
  for (int r = 0; r < 8; ++r) {
    float sv = acc[r] * asw;
    float dv = acc[r] * adw;
#pragma unroll
    for (int mm = 32; mm >= 1; mm >>= 1) {
      sv += __shfl_xor(sv, mm);
      dv += __shfl_xor(dv, mm);
    }
    if (lane == 0) {
      const int i = i0 + rg * 8 + r;
      s_src[(size_t)h * NN + i] = sv;
      d_dst[(size_t)h * NN + i] = dv;
    }
  }
}

// ---------------------------------------------------------------------------
// K2: maxd[h] = max_j d_dst[h][j]  (upper bound for softmax stabilization)
// ---------------------------------------------------------------------------
__global__ __launch_bounds__(1024) void k2_maxd(
    const float* __restrict__ d_dst, float* __restrict__ maxd)
{
  __shared__ float red[16];
  const int h = blockIdx.x;
  const int t = threadIdx.x;
  float mx = -3.4e38f;
  for (int idx = t; idx < NN; idx += 1024)
    mx = fmaxf(mx, d_dst[(size_t)h * NN + idx]);
#pragma unroll
  for (int mm = 32; mm >= 1; mm >>= 1) mx = fmaxf(mx, __shfl_xor(mx, mm));
  if ((t & 63) == 0) red[t >> 6] = mx;
  __syncthreads();
  if (t == 0) {
    float m2 = red[0];
#pragma unroll
    for (int q = 1; q < 16; ++q) m2 = fmaxf(m2, red[q]);
    maxd[h] = m2;
  }
}

// ---------------------------------------------------------------------------
// K3: masked rank-1-score softmax + PV (bf16 MFMA), partial over half of j.
// grid (256, 2): 16-row tile x j-half. block 1024 = 16 waves (wv = jq*4 + h).
// Each wave covers 512 j. Single-barrier LDS tree-merge across jq, then
// jhalf-partials -> ws (merged in K4). Upper-bound stabilizer => partial
// sums merge by plain addition.
// ---------------------------------------------------------------------------
__global__ __launch_bounds__(1024) void k3_attn(
    const u8* __restrict__ mask,
    const u16* __restrict__ WxT,
    const float* __restrict__ s_src, const float* __restrict__ d_dst,
    const float* __restrict__ maxd,
    float* __restrict__ Pp, float* __restrict__ Sp)
{
  const int i0 = blockIdx.x * 16;
  const int jhalf = blockIdx.y;
  const int t = threadIdx.x;
  const int wv = t >> 6;
  const int lane = t & 63;
  const int h = wv & 3;
  const int jq = wv >> 2;
  const int rloc = lane & 15;
  const int g = lane >> 4;
  const int i = i0 + rloc;

  __shared__ float lacc[16][16][66];  // [wave][row][col], pad 66: conflict-free
  __shared__ float lsum[16][16];

  const int base = (jhalf * 4 + jq) * 512;

  const float si = s_src[(size_t)h * NN + i];
  const float e0 = si + maxd[h];
  const float m = fmaxf(e0, NEG_SLOPE * e0);   // leaky monotone => valid ub

  f32x4 acc[4] = {};
  float sump = 0.f;

  const u8* mrow = mask + (size_t)i * (NN / 8) + (base >> 3);
  const float* dh = d_dst + (size_t)h * NN;

  for (int step = 0; step < 16; ++step) {
    const int jb = base + step * 32 + g * 8;
    const u32 m32 = *reinterpret_cast<const u32*>(mrow + step * 4);
    const u32 mb = (m32 >> (g * 8)) & 0xffu;
    const float4 dv0 = *reinterpret_cast<const float4*>(dh + jb);
    const float4 dv1 = *reinterpret_cast<const float4*>(dh + jb + 4);
    const float dvv[8] = {dv0.x, dv0.y, dv0.z, dv0.w, dv1.x, dv1.y, dv1.z, dv1.w};
    short8 af;
#pragma unroll
    for (int e = 0; e < 8; ++e) {
      const float ev = si + dvv[e];
      const float lv = fmaxf(ev, NEG_SLOPE * ev);
      const float pe = __expf(lv - m);
      const float pv = ((mb >> e) & 1u) ? pe : 0.f;
      sump += pv;
      __hip_bfloat16 bb = __float2bfloat16(pv);
      af[e] = *reinterpret_cast<const short*>(&bb);
    }
#pragma unroll
    for (int dt = 0; dt < 4; ++dt) {
      const int d = dt * 16 + rloc;
      const short8 bfr = *reinterpret_cast<const short8*>(
          WxT + (size_t)(h * HD + d) * NN + jb);
      acc[dt] = __builtin_amdgcn_mfma_f32_16x16x32_bf16(af, bfr, acc[dt], 0, 0, 0);
    }
  }

  // full row-sum across the 4 k-groups
  sump += __shfl_xor(sump, 16);
  sump += __shfl_xor(sump, 32);

  // dump per-wave tiles to LDS, one barrier, tree-merge the 4 jq slices
#pragma unroll
  for (int dt = 0; dt < 4; ++dt)
#pragma unroll
    for (int q = 0; q < 4; ++q)
      lacc[wv][g * 4 + q][dt * 16 + rloc] = acc[dt][q];
  if (lane < 16) lsum[wv][lane] = sump;
  __syncthreads();

  {
    const int c = t & 63;
    const int r = t >> 6;
    float* Pb = Pp + (size_t)jhalf * NN * OUT_DIM + (size_t)(i0 + r) * OUT_DIM;
#pragma unroll
    for (int hh = 0; hh < NH; ++hh) {
      const float v = lacc[hh][r][c] + lacc[4 + hh][r][c] +
                      lacc[8 + hh][r][c] + lacc[12 + hh][r][c];
      Pb[hh * HD + c] = v;
    }
  }
  if (t < 64) {
    const int hh = t >> 4;
    const int r = t & 15;
    Sp[((size_t)jhalf * NH + hh) * NN + i0 + r] =
        lsum[hh][r] + lsum[4 + hh][r] + lsum[8 + hh][r] + lsum[12 + hh][r];
  }
}

// ---------------------------------------------------------------------------
// K4: merge halves, normalize, ELU, LayerNorm, store.
// grid 256 (16 rows/block), block 256 = 4 waves; wave handles 4 rows.
// ---------------------------------------------------------------------------
__global__ __launch_bounds__(256) void k4_final(
    const float* __restrict__ Pp, const float* __restrict__ Sp,
    const float* __restrict__ gamma, const float* __restrict__ beta,
    float* __restrict__ out)
{
  const int i0 = blockIdx.x * 16;
  const int t = threadIdx.x;
  const int wv = t >> 6;
  const int lane = t & 63;

  for (int rr = 0; rr < 4; ++rr) {
    const int i = i0 + wv * 4 + rr;
    float xv[4];
    float sum = 0.f, sq = 0.f;
#pragma unroll
    for (int q = 0; q < 4; ++q) {
      const int c = q * 64 + lane;
      const float denom = Sp[(size_t)q * NN + i] + Sp[((size_t)NH + q) * NN + i];
      float v = (Pp[(size_t)i * OUT_DIM + c] +
                 Pp[(size_t)NN * OUT_DIM + (size_t)i * OUT_DIM + c]) / denom;
      v = (v > 0.f) ? v : expm1f(v);
      xv[q] = v;
      sum += v;
      sq += v * v;
    }
#pragma unroll
    for (int mm = 32; mm >= 1; mm >>= 1) {
      sum += __shfl_xor(sum, mm);
      sq += __shfl_xor(sq, mm);
    }
    const float mu = sum * (1.f / OUT_DIM);
    const float var = sq * (1.f / OUT_DIM) - mu * mu;
    const float rs = rsqrtf(var + LN_EPS);
#pragma unroll
    for (int q = 0; q < 4; ++q) {
      const int c = q * 64 + lane;
      out[(size_t)i * OUT_DIM + c] = (xv[q] - mu) * rs * gamma[c] + beta[c];
    }
  }
}

extern "C" void kernel_launch(void* const* d_in, const int* in_sizes, int n_in,
                              void* d_out, int out_size, void* d_ws, size_t ws_size,
                              hipStream_t stream) {
  const float* x = (const float*)d_in[0];
  const int* adj = (const int*)d_in[1];
  const float* W = (const float*)d_in[2];
  const float* a = (const float*)d_in[3];
  const float* gamma = (const float*)d_in[4];
  const float* beta = (const float*)d_in[5];
  float* out = (float*)d_out;

  char* ws = (char*)d_ws;
  size_t off = 0;
  u16* WxT = (u16*)(ws + off);            off += (size_t)NH * HD * NN * 2;      // 2 MiB
  float* s_src = (float*)(ws + off);      off += (size_t)NH * NN * 4;           // 64 KiB
  float* d_dst = (float*)(ws + off);      off += (size_t)NH * NN * 4;           // 64 KiB
  float* maxd = (float*)(ws + off);       off += 256;
  u64* mask = (u64*)(ws + off);           off += (size_t)NN * (NN / 8);         // 2 MiB
  float* Pp = (float*)(ws + off);         off += (size_t)2 * NN * OUT_DIM * 4;  // 8 MiB
  float* Sp = (float*)(ws + off);         off += (size_t)2 * NH * NN * 4;       // 128 KiB

  k0_pack<<<dim3(NN), dim3(1024), 0, stream>>>(adj, mask);
  k1_proj<<<dim3(512), dim3(256), 0, stream>>>(x, W, a, WxT, s_src, d_dst);
  k2_maxd<<<dim3(NH), dim3(1024), 0, stream>>>(d_dst, maxd);
  k3_attn<<<dim3(256, 2), dim3(1024), 0, stream>>>((const u8*)mask, WxT, s_src,
                                                   d_dst, maxd, Pp, Sp);
  k4_final<<<dim3(256), dim3(256), 0, stream>>>(Pp, Sp, gamma, beta, out);
}

// Round 4
// 143.550 us; speedup vs baseline: 1.0479x; 1.0357x over previous
//
#include <hip/hip_runtime.h>
#include <hip/hip_bf16.h>

#define NN 4096
#define IN_DIM 512
#define OUT_DIM 256
#define NH 4
#define HD 64
#define NEG_SLOPE 0.2f
#define LN_EPS 1e-5f

typedef __attribute__((ext_vector_type(8))) short short8;
typedef __attribute__((ext_vector_type(4))) float f32x4;
typedef unsigned short u16;
typedef unsigned int u32;
typedef unsigned long long u64;
typedef unsigned char u8;

// ---------------------------------------------------------------------------
// K0: pack (adj>0)|I into a bitmask [NN][NN/8 bytes], self-loops folded in.
// grid 512 (8 rows/block), block 1024. int4 loads: 32B/lane, fully coalesced.
// ---------------------------------------------------------------------------
__global__ __launch_bounds__(1024) void k0_pack(
    const int* __restrict__ adj, u8* __restrict__ mask)
{
  const int b = blockIdx.x;
  const int t = threadIdx.x;
#pragma unroll
  for (int it = 0; it < 4; ++it) {
    const int row = b * 8 + it * 2 + (t >> 9);
    const int byte = t & 511;
    const int j0 = byte * 8;
    const int4 v0 = *reinterpret_cast<const int4*>(adj + (size_t)row * NN + j0);
    const int4 v1 = *reinterpret_cast<const int4*>(adj + (size_t)row * NN + j0 + 4);
    const int vv[8] = {v0.x, v0.y, v0.z, v0.w, v1.x, v1.y, v1.z, v1.w};
    u32 bbits = 0;
#pragma unroll
    for (int c = 0; c < 8; ++c)
      if ((vv[c] > 0) || (row == j0 + c)) bbits |= (1u << c);
    mask[(size_t)row * (NN / 8) + byte] = (u8)bbits;
  }
}

// ---------------------------------------------------------------------------
// K1: Wx[h] = x @ W[h]  (f32 accum). Epilogue: WxT bf16 [h][d][j], s_src, d_dst.
// grid 512 (h*128 + rowtile), block 256. Tile: 32 rows x 64 cols, K-chunks of 32.
// ---------------------------------------------------------------------------
__global__ __launch_bounds__(256) void k1_proj(
    const float* __restrict__ x, const float* __restrict__ W,
    const float* __restrict__ a,
    u16* __restrict__ WxT,
    float* __restrict__ s_src,
    float* __restrict__ d_dst)
{
  const int b = blockIdx.x;
  const int h = b >> 7;
  const int i0 = (b & 127) * 32;
  const int t = threadIdx.x;
  const int lane = t & 63;   // output col d
  const int rg = t >> 6;     // wave id -> rows rg*8 .. rg*8+7

  __shared__ float xT[32][34];   // [kk][row]
  __shared__ float Wl[32][64];   // [kk][d]

  float acc[8];
#pragma unroll
  for (int r = 0; r < 8; ++r) acc[r] = 0.f;

  for (int k0 = 0; k0 < IN_DIM; k0 += 32) {
    __syncthreads();
    {
      const int r = t >> 3;
      const int kg = t & 7;
      const float4 xv = *reinterpret_cast<const float4*>(
          x + (size_t)(i0 + r) * IN_DIM + k0 + kg * 4);
      xT[kg * 4 + 0][r] = xv.x;
      xT[kg * 4 + 1][r] = xv.y;
      xT[kg * 4 + 2][r] = xv.z;
      xT[kg * 4 + 3][r] = xv.w;
    }
    {
      const int kk0 = t >> 6;
#pragma unroll
      for (int i2 = 0; i2 < 8; ++i2) {
        const int kk = kk0 * 8 + i2;
        Wl[kk][lane] = W[((size_t)h * IN_DIM + k0 + kk) * HD + lane];
      }
    }
    __syncthreads();
#pragma unroll 4
    for (int kk = 0; kk < 32; ++kk) {
      const float w = Wl[kk][lane];
      const float2* xp = reinterpret_cast<const float2*>(&xT[kk][rg * 8]);
      const float2 x01 = xp[0], x23 = xp[1], x45 = xp[2], x67 = xp[3];
      acc[0] = fmaf(x01.x, w, acc[0]);
      acc[1] = fmaf(x01.y, w, acc[1]);
      acc[2] = fmaf(x23.x, w, acc[2]);
      acc[3] = fmaf(x23.y, w, acc[3]);
      acc[4] = fmaf(x45.x, w, acc[4]);
      acc[5] = fmaf(x45.y, w, acc[5]);
      acc[6] = fmaf(x67.x, w, acc[6]);
      acc[7] = fmaf(x67.y, w, acc[7]);
    }
  }

  // ---- epilogue: bf16 transpose-store + attention scalars ----
  const float asw = a[(size_t)h * 2 * HD + lane];
  const float adw = a[(size_t)h * 2 * HD + HD + lane];

  u16 us[8];
#pragma unroll
  for (int r = 0; r < 8; ++r) {
    __hip_bfloat16 bv = __float2bfloat16(acc[r]);
    us[r] = *reinterpret_cast<const u16*>(&bv);
  }
  uint4 pk;
  pk.x = (u32)us[0] | ((u32)us[1] << 16);
  pk.y = (u32)us[2] | ((u32)us[3] << 16);
  pk.z = (u32)us[4] | ((u32)us[5] << 16);
  pk.w = (u32)us[6] | ((u32)us[7] << 16);
  *reinterpret_cast<uint4*>(WxT + (size_t)(h * HD + lane) * NN + i0 + rg * 8) = pk;

#pragma unroll
  for (int r = 0; r < 8; ++r) {
    float sv = acc[r] * asw;
    float dv = acc[r] * adw;
#pragma unroll
    for (int mm = 32; mm >= 1; mm >>= 1) {
      sv += __shfl_xor(sv, mm);
      dv += __shfl_xor(dv, mm);
    }
    if (lane == 0) {
      const int i = i0 + rg * 8 + r;
      s_src[(size_t)h * NN + i] = sv;
      d_dst[(size_t)h * NN + i] = dv;
    }
  }
}

// ---------------------------------------------------------------------------
// K2: maxd[h] = max_j d_dst[h][j]  (upper bound for softmax stabilization)
// ---------------------------------------------------------------------------
__global__ __launch_bounds__(1024) void k2_maxd(
    const float* __restrict__ d_dst, float* __restrict__ maxd)
{
  __shared__ float red[16];
  const int h = blockIdx.x;
  const int t = threadIdx.x;
  float mx = -3.4e38f;
  for (int idx = t; idx < NN; idx += 1024)
    mx = fmaxf(mx, d_dst[(size_t)h * NN + idx]);
#pragma unroll
  for (int mm = 32; mm >= 1; mm >>= 1) mx = fmaxf(mx, __shfl_xor(mx, mm));
  if ((t & 63) == 0) red[t >> 6] = mx;
  __syncthreads();
  if (t == 0) {
    float m2 = red[0];
#pragma unroll
    for (int q = 1; q < 16; ++q) m2 = fmaxf(m2, red[q]);
    maxd[h] = m2;
  }
}

// ---------------------------------------------------------------------------
// K3: masked rank-1-score softmax + PV (bf16 MFMA), 1-deep software prefetch.
// grid (128, 2): 32-row i-tile x j-half. block 1024 = 16 waves:
//   wv = jsub*8 + isub*4 + h; wave covers 16 rows (isub) x 1024 j (jsub),
//   32 K-steps of 32 j, all loads for step k+1 issued before step k's compute.
// jsub-pair merge in LDS (one barrier); jhalf partials -> ws (merged in K4).
// Upper-bound stabilizer m => partials merge by plain addition.
// ---------------------------------------------------------------------------
__global__ __launch_bounds__(1024) void k3_attn(
    const u8* __restrict__ mask,
    const u16* __restrict__ WxT,
    const float* __restrict__ s_src, const float* __restrict__ d_dst,
    const float* __restrict__ maxd,
    float* __restrict__ Pp, float* __restrict__ Sp)
{
  const int bx = blockIdx.x;
  const int jhalf = blockIdx.y;
  const int t = threadIdx.x;
  const int wv = t >> 6;
  const int lane = t & 63;
  const int h = wv & 3;
  const int isub = (wv >> 2) & 1;
  const int jsub = wv >> 3;
  const int rloc = lane & 15;
  const int g = lane >> 4;
  const int i0w = bx * 32 + isub * 16;
  const int i = i0w + rloc;
  const int jbase = jhalf * 2048 + jsub * 1024;

  __shared__ float lacc[8][16][66];   // jsub=1 partials, pad 66 (<=2-way banks)
  __shared__ float lsum[8][16];

  const float si = s_src[(size_t)h * NN + i];
  const float e0 = si + maxd[h];
  const float m = fmaxf(e0, NEG_SLOPE * e0);   // leaky monotone => valid ub

  f32x4 acc[4] = {};
  float sump = 0.f;

  const u8* mrow = mask + (size_t)i * (NN / 8) + (jbase >> 3);
  const float* dh = d_dst + (size_t)h * NN;
  const u16* wb = WxT + (size_t)(h * HD + rloc) * NN;

  // --- prefetch step 0 ---
  u32 mC;
  float4 dC0, dC1;
  short8 wC0, wC1, wC2, wC3;
  {
    const int jb = jbase + g * 8;
    mC = *reinterpret_cast<const u32*>(mrow);
    dC0 = *reinterpret_cast<const float4*>(dh + jb);
    dC1 = *reinterpret_cast<const float4*>(dh + jb + 4);
    wC0 = *reinterpret_cast<const short8*>(wb + jb);
    wC1 = *reinterpret_cast<const short8*>(wb + 16 * NN + jb);
    wC2 = *reinterpret_cast<const short8*>(wb + 32 * NN + jb);
    wC3 = *reinterpret_cast<const short8*>(wb + 48 * NN + jb);
  }

  for (int step = 0; step < 32; ++step) {
    // --- issue next step's loads before this step's compute ---
    const int pstep = (step < 31) ? step + 1 : 31;
    const int jbn = jbase + pstep * 32 + g * 8;
    const u32 mN = *reinterpret_cast<const u32*>(mrow + pstep * 4);
    const float4 dN0 = *reinterpret_cast<const float4*>(dh + jbn);
    const float4 dN1 = *reinterpret_cast<const float4*>(dh + jbn + 4);
    const short8 wN0 = *reinterpret_cast<const short8*>(wb + jbn);
    const short8 wN1 = *reinterpret_cast<const short8*>(wb + 16 * NN + jbn);
    const short8 wN2 = *reinterpret_cast<const short8*>(wb + 32 * NN + jbn);
    const short8 wN3 = *reinterpret_cast<const short8*>(wb + 48 * NN + jbn);

    // --- compute on current regs ---
    const u32 mb = (mC >> (g * 8)) & 0xffu;
    const float dvv[8] = {dC0.x, dC0.y, dC0.z, dC0.w, dC1.x, dC1.y, dC1.z, dC1.w};
    short8 af;
#pragma unroll
    for (int e = 0; e < 8; ++e) {
      const float ev = si + dvv[e];
      const float lv = fmaxf(ev, NEG_SLOPE * ev);
      const float pe = __expf(lv - m);
      const float pv = ((mb >> e) & 1u) ? pe : 0.f;
      sump += pv;
      __hip_bfloat16 bb = __float2bfloat16(pv);
      af[e] = *reinterpret_cast<const short*>(&bb);
    }
    acc[0] = __builtin_amdgcn_mfma_f32_16x16x32_bf16(af, wC0, acc[0], 0, 0, 0);
    acc[1] = __builtin_amdgcn_mfma_f32_16x16x32_bf16(af, wC1, acc[1], 0, 0, 0);
    acc[2] = __builtin_amdgcn_mfma_f32_16x16x32_bf16(af, wC2, acc[2], 0, 0, 0);
    acc[3] = __builtin_amdgcn_mfma_f32_16x16x32_bf16(af, wC3, acc[3], 0, 0, 0);

    mC = mN; dC0 = dN0; dC1 = dN1;
    wC0 = wN0; wC1 = wN1; wC2 = wN2; wC3 = wN3;
  }

  // full row-sum across the 4 k-groups (all lanes end with row rloc's total)
  sump += __shfl_xor(sump, 16);
  sump += __shfl_xor(sump, 32);

  // jsub=1 waves dump to LDS; one barrier; jsub=0 waves merge + write partials
  if (jsub == 1) {
    const int s = wv & 7;
#pragma unroll
    for (int dt = 0; dt < 4; ++dt)
#pragma unroll
      for (int q = 0; q < 4; ++q)
        lacc[s][g * 4 + q][dt * 16 + rloc] = acc[dt][q];
    if (lane < 16) lsum[s][lane] = sump;
  }
  __syncthreads();
  if (jsub == 0) {
#pragma unroll
    for (int dt = 0; dt < 4; ++dt)
#pragma unroll
      for (int q = 0; q < 4; ++q)
        acc[dt][q] += lacc[wv][g * 4 + q][dt * 16 + rloc];
    float* Pb = Pp + (size_t)jhalf * NN * OUT_DIM;
#pragma unroll
    for (int dt = 0; dt < 4; ++dt)
#pragma unroll
      for (int q = 0; q < 4; ++q)
        Pb[(size_t)(i0w + g * 4 + q) * OUT_DIM + h * HD + dt * 16 + rloc] =
            acc[dt][q];
    if (lane < 16)
      Sp[((size_t)jhalf * NH + h) * NN + i0w + lane] = sump + lsum[wv][lane];
  }
}

// ---------------------------------------------------------------------------
// K4: merge halves, normalize, ELU, LayerNorm, store.
// grid 256 (16 rows/block), block 256 = 4 waves; wave handles 4 rows.
// ---------------------------------------------------------------------------
__global__ __launch_bounds__(256) void k4_final(
    const float* __restrict__ Pp, const float* __restrict__ Sp,
    const float* __restrict__ gamma, const float* __restrict__ beta,
    float* __restrict__ out)
{
  const int i0 = blockIdx.x * 16;
  const int t = threadIdx.x;
  const int wv = t >> 6;
  const int lane = t & 63;

  for (int rr = 0; rr < 4; ++rr) {
    const int i = i0 + wv * 4 + rr;
    float xv[4];
    float sum = 0.f, sq = 0.f;
#pragma unroll
    for (int q = 0; q < 4; ++q) {
      const int c = q * 64 + lane;
      const float denom = Sp[(size_t)q * NN + i] + Sp[((size_t)NH + q) * NN + i];
      float v = (Pp[(size_t)i * OUT_DIM + c] +
                 Pp[(size_t)NN * OUT_DIM + (size_t)i * OUT_DIM + c]) / denom;
      v = (v > 0.f) ? v : expm1f(v);
      xv[q] = v;
      sum += v;
      sq += v * v;
    }
#pragma unroll
    for (int mm = 32; mm >= 1; mm >>= 1) {
      sum += __shfl_xor(sum, mm);
      sq += __shfl_xor(sq, mm);
    }
    const float mu = sum * (1.f / OUT_DIM);
    const float var = sq * (1.f / OUT_DIM) - mu * mu;
    const float rs = rsqrtf(var + LN_EPS);
#pragma unroll
    for (int q = 0; q < 4; ++q) {
      const int c = q * 64 + lane;
      out[(size_t)i * OUT_DIM + c] = (xv[q] - mu) * rs * gamma[c] + beta[c];
    }
  }
}

extern "C" void kernel_launch(void* const* d_in, const int* in_sizes, int n_in,
                              void* d_out, int out_size, void* d_ws, size_t ws_size,
                              hipStream_t stream) {
  const float* x = (const float*)d_in[0];
  const int* adj = (const int*)d_in[1];
  const float* W = (const float*)d_in[2];
  const float* a = (const float*)d_in[3];
  const float* gamma = (const float*)d_in[4];
  const float* beta = (const float*)d_in[5];
  float* out = (float*)d_out;

  char* ws = (char*)d_ws;
  size_t off = 0;
  u16* WxT = (u16*)(ws + off);            off += (size_t)NH * HD * NN * 2;      // 2 MiB
  float* s_src = (float*)(ws + off);      off += (size_t)NH * NN * 4;           // 64 KiB
  float* d_dst = (float*)(ws + off);      off += (size_t)NH * NN * 4;           // 64 KiB
  float* maxd = (float*)(ws + off);       off += 256;
  u8* mask = (u8*)(ws + off);             off += (size_t)NN * (NN / 8);         // 2 MiB
  float* Pp = (float*)(ws + off);         off += (size_t)2 * NN * OUT_DIM * 4;  // 8 MiB
  float* Sp = (float*)(ws + off);         off += (size_t)2 * NH * NN * 4;       // 128 KiB

  k0_pack<<<dim3(512), dim3(1024), 0, stream>>>(adj, mask);
  k1_proj<<<dim3(512), dim3(256), 0, stream>>>(x, W, a, WxT, s_src, d_dst);
  k2_maxd<<<dim3(NH), dim3(1024), 0, stream>>>(d_dst, maxd);
  k3_attn<<<dim3(128, 2), dim3(1024), 0, stream>>>(mask, WxT, s_src,
                                                   d_dst, maxd, Pp, Sp);
  k4_final<<<dim3(256), dim3(256), 0, stream>>>(Pp, Sp, gamma, beta, out);
}

// Round 5
// 143.524 us; speedup vs baseline: 1.0481x; 1.0002x over previous
//
#include <hip/hip_runtime.h>
#include <hip/hip_bf16.h>

#define NN 4096
#define IN_DIM 512
#define OUT_DIM 256
#define NH 4
#define HD 64
#define NEG_SLOPE 0.2f
#define LN_EPS 1e-5f
#define LOG2E 1.4426950408889634f
#define PITCH 4160   // WxT row pitch in elements (8320 B = 65*128 B: breaks L1-set/L2-channel aliasing)

typedef __attribute__((ext_vector_type(8))) short short8;
typedef __attribute__((ext_vector_type(4))) float f32x4;
typedef unsigned short u16;
typedef unsigned int u32;
typedef unsigned long long u64;
typedef unsigned char u8;

// ---------------------------------------------------------------------------
// K0: pack (adj>0)|I into a bitmask [NN][NN/8 bytes], self-loops folded in.
// grid 512 (8 rows/block), block 1024. int4 loads: 32B/lane, fully coalesced.
// ---------------------------------------------------------------------------
__global__ __launch_bounds__(1024) void k0_pack(
    const int* __restrict__ adj, u8* __restrict__ mask)
{
  const int b = blockIdx.x;
  const int t = threadIdx.x;
#pragma unroll
  for (int it = 0; it < 4; ++it) {
    const int row = b * 8 + it * 2 + (t >> 9);
    const int byte = t & 511;
    const int j0 = byte * 8;
    const int4 v0 = *reinterpret_cast<const int4*>(adj + (size_t)row * NN + j0);
    const int4 v1 = *reinterpret_cast<const int4*>(adj + (size_t)row * NN + j0 + 4);
    const int vv[8] = {v0.x, v0.y, v0.z, v0.w, v1.x, v1.y, v1.z, v1.w};
    u32 bbits = 0;
#pragma unroll
    for (int c = 0; c < 8; ++c)
      if ((vv[c] > 0) || (row == j0 + c)) bbits |= (1u << c);
    mask[(size_t)row * (NN / 8) + byte] = (u8)bbits;
  }
}

// ---------------------------------------------------------------------------
// K1: Wx[h] = x @ W[h]  (f32 accum). Epilogue: WxT bf16 [h*HD+d][PITCH] (padded),
// s_src (raw), d_dst (pre-scaled by log2e). grid 512, block 256.
// ---------------------------------------------------------------------------
__global__ __launch_bounds__(256) void k1_proj(
    const float* __restrict__ x, const float* __restrict__ W,
    const float* __restrict__ a,
    u16* __restrict__ WxT,
    float* __restrict__ s_src,
    float* __restrict__ d_dst)
{
  const int b = blockIdx.x;
  const int h = b >> 7;
  const int i0 = (b & 127) * 32;
  const int t = threadIdx.x;
  const int lane = t & 63;   // output col d
  const int rg = t >> 6;     // wave id -> rows rg*8 .. rg*8+7

  __shared__ float xT[32][34];   // [kk][row]
  __shared__ float Wl[32][64];   // [kk][d]

  float acc[8];
#pragma unroll
  for (int r = 0; r < 8; ++r) acc[r] = 0.f;

  for (int k0 = 0; k0 < IN_DIM; k0 += 32) {
    __syncthreads();
    {
      const int r = t >> 3;
      const int kg = t & 7;
      const float4 xv = *reinterpret_cast<const float4*>(
          x + (size_t)(i0 + r) * IN_DIM + k0 + kg * 4);
      xT[kg * 4 + 0][r] = xv.x;
      xT[kg * 4 + 1][r] = xv.y;
      xT[kg * 4 + 2][r] = xv.z;
      xT[kg * 4 + 3][r] = xv.w;
    }
    {
      const int kk0 = t >> 6;
#pragma unroll
      for (int i2 = 0; i2 < 8; ++i2) {
        const int kk = kk0 * 8 + i2;
        Wl[kk][lane] = W[((size_t)h * IN_DIM + k0 + kk) * HD + lane];
      }
    }
    __syncthreads();
#pragma unroll 4
    for (int kk = 0; kk < 32; ++kk) {
      const float w = Wl[kk][lane];
      const float2* xp = reinterpret_cast<const float2*>(&xT[kk][rg * 8]);
      const float2 x01 = xp[0], x23 = xp[1], x45 = xp[2], x67 = xp[3];
      acc[0] = fmaf(x01.x, w, acc[0]);
      acc[1] = fmaf(x01.y, w, acc[1]);
      acc[2] = fmaf(x23.x, w, acc[2]);
      acc[3] = fmaf(x23.y, w, acc[3]);
      acc[4] = fmaf(x45.x, w, acc[4]);
      acc[5] = fmaf(x45.y, w, acc[5]);
      acc[6] = fmaf(x67.x, w, acc[6]);
      acc[7] = fmaf(x67.y, w, acc[7]);
    }
  }

  // ---- epilogue: bf16 transpose-store (padded pitch) + attention scalars ----
  const float asw = a[(size_t)h * 2 * HD + lane];
  const float adw = a[(size_t)h * 2 * HD + HD + lane];

  u16 us[8];
#pragma unroll
  for (int r = 0; r < 8; ++r) {
    __hip_bfloat16 bv = __float2bfloat16(acc[r]);
    us[r] = *reinterpret_cast<const u16*>(&bv);
  }
  uint4 pk;
  pk.x = (u32)us[0] | ((u32)us[1] << 16);
  pk.y = (u32)us[2] | ((u32)us[3] << 16);
  pk.z = (u32)us[4] | ((u32)us[5] << 16);
  pk.w = (u32)us[6] | ((u32)us[7] << 16);
  *reinterpret_cast<uint4*>(WxT + (size_t)(h * HD + lane) * PITCH + i0 + rg * 8) = pk;

#pragma unroll
  for (int r = 0; r < 8; ++r) {
    float sv = acc[r] * asw;
    float dv = acc[r] * adw;
#pragma unroll
    for (int mm = 32; mm >= 1; mm >>= 1) {
      sv += __shfl_xor(sv, mm);
      dv += __shfl_xor(dv, mm);
    }
    if (lane == 0) {
      const int i = i0 + rg * 8 + r;
      s_src[(size_t)h * NN + i] = sv;
      d_dst[(size_t)h * NN + i] = dv * LOG2E;   // log2-domain
    }
  }
}

// ---------------------------------------------------------------------------
// K2: maxd2[h] = max_j d2[h][j]  (upper bound for softmax stabilization)
// ---------------------------------------------------------------------------
__global__ __launch_bounds__(1024) void k2_maxd(
    const float* __restrict__ d_dst, float* __restrict__ maxd)
{
  __shared__ float red[16];
  const int h = blockIdx.x;
  const int t = threadIdx.x;
  float mx = -3.4e38f;
  for (int idx = t; idx < NN; idx += 1024)
    mx = fmaxf(mx, d_dst[(size_t)h * NN + idx]);
#pragma unroll
  for (int mm = 32; mm >= 1; mm >>= 1) mx = fmaxf(mx, __shfl_xor(mx, mm));
  if ((t & 63) == 0) red[t >> 6] = mx;
  __syncthreads();
  if (t == 0) {
    float m2 = red[0];
#pragma unroll
    for (int q = 1; q < 16; ++q) m2 = fmaxf(m2, red[q]);
    maxd[h] = m2;
  }
}

// ---------------------------------------------------------------------------
// K3: masked rank-1-score softmax (log2-domain) + PV (bf16 MFMA).
// grid (256, 2): 16-row tile x j-half. block 1024 = 16 waves (wv = jq*4 + h).
// Each wave covers 512 j (16 steps of 32). Single-barrier LDS tree-merge
// across jq; jhalf partials -> ws (merged in K4). Upper-bound stabilizer
// => partials merge by plain addition. WxT reads use padded PITCH.
// ---------------------------------------------------------------------------
__global__ __launch_bounds__(1024) void k3_attn(
    const u8* __restrict__ mask,
    const u16* __restrict__ WxT,
    const float* __restrict__ s_src, const float* __restrict__ d_dst,
    const float* __restrict__ maxd,
    float* __restrict__ Pp, float* __restrict__ Sp)
{
  const int i0 = blockIdx.x * 16;
  const int jhalf = blockIdx.y;
  const int t = threadIdx.x;
  const int wv = t >> 6;
  const int lane = t & 63;
  const int h = wv & 3;
  const int jq = wv >> 2;
  const int rloc = lane & 15;
  const int g = lane >> 4;
  const int i = i0 + rloc;

  __shared__ float lacc[16][16][66];  // [wave][row][col], pad 66
  __shared__ float lsum[16][16];

  const int base = (jhalf * 4 + jq) * 512;

  const float si2 = s_src[(size_t)h * NN + i] * LOG2E;
  const float e02 = si2 + maxd[h];
  const float m2 = fmaxf(e02, NEG_SLOPE * e02);   // log2-domain upper bound

  f32x4 acc[4] = {};
  float sump = 0.f;

  const u32* mrow = reinterpret_cast<const u32*>(
      mask + (size_t)i * (NN / 8) + (base >> 3));
  const float* dh = d_dst + (size_t)h * NN + base;
  const u16* wb = WxT + (size_t)(h * HD + rloc) * PITCH + base;

  u32 jo = g * 8;   // element offset within the wave's 512-j window
  for (int step = 0; step < 16; ++step) {
    const u32 m32 = mrow[step];
    const float4 dv0 = *reinterpret_cast<const float4*>(dh + jo);
    const float4 dv1 = *reinterpret_cast<const float4*>(dh + jo + 4);
    const short8 w0 = *reinterpret_cast<const short8*>(wb + jo);
    const short8 w1 = *reinterpret_cast<const short8*>(wb + 16 * PITCH + jo);
    const short8 w2 = *reinterpret_cast<const short8*>(wb + 32 * PITCH + jo);
    const short8 w3 = *reinterpret_cast<const short8*>(wb + 48 * PITCH + jo);

    const u32 mb = (m32 >> (g * 8)) & 0xffu;
    const float dvv[8] = {dv0.x, dv0.y, dv0.z, dv0.w, dv1.x, dv1.y, dv1.z, dv1.w};
    short8 af;
#pragma unroll
    for (int e = 0; e < 8; ++e) {
      const float ev = si2 + dvv[e];
      const float lv = fmaxf(ev, NEG_SLOPE * ev);
      const float xx = lv - m2;
      float pe;
      asm("v_exp_f32 %0, %1" : "=v"(pe) : "v"(xx));   // 2^xx
      const float pv = ((mb >> e) & 1u) ? pe : 0.f;
      sump += pv;
      __hip_bfloat16 bb = __float2bfloat16(pv);
      af[e] = *reinterpret_cast<const short*>(&bb);
    }
    acc[0] = __builtin_amdgcn_mfma_f32_16x16x32_bf16(af, w0, acc[0], 0, 0, 0);
    acc[1] = __builtin_amdgcn_mfma_f32_16x16x32_bf16(af, w1, acc[1], 0, 0, 0);
    acc[2] = __builtin_amdgcn_mfma_f32_16x16x32_bf16(af, w2, acc[2], 0, 0, 0);
    acc[3] = __builtin_amdgcn_mfma_f32_16x16x32_bf16(af, w3, acc[3], 0, 0, 0);
    jo += 32;
  }

  // full row-sum across the 4 k-groups
  sump += __shfl_xor(sump, 16);
  sump += __shfl_xor(sump, 32);

  // dump per-wave tiles to LDS, one barrier, tree-merge the 4 jq slices
#pragma unroll
  for (int dt = 0; dt < 4; ++dt)
#pragma unroll
    for (int q = 0; q < 4; ++q)
      lacc[wv][g * 4 + q][dt * 16 + rloc] = acc[dt][q];
  if (lane < 16) lsum[wv][lane] = sump;
  __syncthreads();

  {
    const int c = t & 63;
    const int r = t >> 6;
    float* Pb = Pp + (size_t)jhalf * NN * OUT_DIM + (size_t)(i0 + r) * OUT_DIM;
#pragma unroll
    for (int hh = 0; hh < NH; ++hh) {
      const float v = lacc[hh][r][c] + lacc[4 + hh][r][c] +
                      lacc[8 + hh][r][c] + lacc[12 + hh][r][c];
      Pb[hh * HD + c] = v;
    }
  }
  if (t < 64) {
    const int hh = t >> 4;
    const int r = t & 15;
    Sp[((size_t)jhalf * NH + hh) * NN + i0 + r] =
        lsum[hh][r] + lsum[4 + hh][r] + lsum[8 + hh][r] + lsum[12 + hh][r];
  }
}

// ---------------------------------------------------------------------------
// K4: merge halves, normalize, ELU, LayerNorm, store.
// grid 256 (16 rows/block), block 256 = 4 waves; wave handles 4 rows.
// ---------------------------------------------------------------------------
__global__ __launch_bounds__(256) void k4_final(
    const float* __restrict__ Pp, const float* __restrict__ Sp,
    const float* __restrict__ gamma, const float* __restrict__ beta,
    float* __restrict__ out)
{
  const int i0 = blockIdx.x * 16;
  const int t = threadIdx.x;
  const int wv = t >> 6;
  const int lane = t & 63;

  for (int rr = 0; rr < 4; ++rr) {
    const int i = i0 + wv * 4 + rr;
    float xv[4];
    float sum = 0.f, sq = 0.f;
#pragma unroll
    for (int q = 0; q < 4; ++q) {
      const int c = q * 64 + lane;
      const float denom = Sp[(size_t)q * NN + i] + Sp[((size_t)NH + q) * NN + i];
      float v = (Pp[(size_t)i * OUT_DIM + c] +
                 Pp[(size_t)NN * OUT_DIM + (size_t)i * OUT_DIM + c]) / denom;
      v = (v > 0.f) ? v : expm1f(v);
      xv[q] = v;
      sum += v;
      sq += v * v;
    }
#pragma unroll
    for (int mm = 32; mm >= 1; mm >>= 1) {
      sum += __shfl_xor(sum, mm);
      sq += __shfl_xor(sq, mm);
    }
    const float mu = sum * (1.f / OUT_DIM);
    const float var = sq * (1.f / OUT_DIM) - mu * mu;
    const float rs = rsqrtf(var + LN_EPS);
#pragma unroll
    for (int q = 0; q < 4; ++q) {
      const int c = q * 64 + lane;
      out[(size_t)i * OUT_DIM + c] = (xv[q] - mu) * rs * gamma[c] + beta[c];
    }
  }
}

extern "C" void kernel_launch(void* const* d_in, const int* in_sizes, int n_in,
                              void* d_out, int out_size, void* d_ws, size_t ws_size,
                              hipStream_t stream) {
  const float* x = (const float*)d_in[0];
  const int* adj = (const int*)d_in[1];
  const float* W = (const float*)d_in[2];
  const float* a = (const float*)d_in[3];
  const float* gamma = (const float*)d_in[4];
  const float* beta = (const float*)d_in[5];
  float* out = (float*)d_out;

  char* ws = (char*)d_ws;
  size_t off = 0;
  u16* WxT = (u16*)(ws + off);            off += (size_t)NH * HD * PITCH * 2;   // 2.03 MiB (padded)
  float* s_src = (float*)(ws + off);      off += (size_t)NH * NN * 4;           // 64 KiB
  float* d_dst = (float*)(ws + off);      off += (size_t)NH * NN * 4;           // 64 KiB
  float* maxd = (float*)(ws + off);       off += 256;
  u8* mask = (u8*)(ws + off);             off += (size_t)NN * (NN / 8);         // 2 MiB
  float* Pp = (float*)(ws + off);         off += (size_t)2 * NN * OUT_DIM * 4;  // 8 MiB
  float* Sp = (float*)(ws + off);         off += (size_t)2 * NH * NN * 4;       // 128 KiB

  k0_pack<<<dim3(512), dim3(1024), 0, stream>>>(adj, mask);
  k1_proj<<<dim3(512), dim3(256), 0, stream>>>(x, W, a, WxT, s_src, d_dst);
  k2_maxd<<<dim3(NH), dim3(1024), 0, stream>>>(d_dst, maxd);
  k3_attn<<<dim3(256, 2), dim3(1024), 0, stream>>>(mask, WxT, s_src,
                                                   d_dst, maxd, Pp, Sp);
  k4_final<<<dim3(256), dim3(256), 0, stream>>>(Pp, Sp, gamma, beta, out);
}

// Round 6
// 88.412 us; speedup vs baseline: 1.7015x; 1.6234x over previous
//
#include <hip/hip_runtime.h>
#include <hip/hip_bf16.h>

#define NN 4096
#define IN_DIM 512
#define OUT_DIM 256
#define NH 4
#define HD 64
#define NEG_SLOPE 0.2f
#define LN_EPS 1e-5f
#define LOG2E 1.4426950408889634f

typedef __attribute__((ext_vector_type(8))) short short8;
typedef __attribute__((ext_vector_type(4))) float f32x4;
typedef unsigned short u16;
typedef unsigned int u32;
typedef unsigned long long u64;
typedef unsigned char u8;

// ---------------------------------------------------------------------------
// K0: pack (adj>0)|I into bitmask [NN][NN/8 B], self-loops folded in.
// ---------------------------------------------------------------------------
__global__ __launch_bounds__(1024) void k0_pack(
    const int* __restrict__ adj, u8* __restrict__ mask)
{
  const int b = blockIdx.x;
  const int t = threadIdx.x;
#pragma unroll
  for (int it = 0; it < 4; ++it) {
    const int row = b * 8 + it * 2 + (t >> 9);
    const int byte = t & 511;
    const int j0 = byte * 8;
    const int4 v0 = *reinterpret_cast<const int4*>(adj + (size_t)row * NN + j0);
    const int4 v1 = *reinterpret_cast<const int4*>(adj + (size_t)row * NN + j0 + 4);
    const int vv[8] = {v0.x, v0.y, v0.z, v0.w, v1.x, v1.y, v1.z, v1.w};
    u32 bbits = 0;
#pragma unroll
    for (int c = 0; c < 8; ++c)
      if ((vv[c] > 0) || (row == j0 + c)) bbits |= (1u << c);
    mask[(size_t)row * (NN / 8) + byte] = (u8)bbits;
  }
}

// ---------------------------------------------------------------------------
// K1: Wx[h] = x @ W[h]. Epilogue: WxT bf16 [h*HD+d][NN], s_src & d_dst ×log2e.
// ---------------------------------------------------------------------------
__global__ __launch_bounds__(256) void k1_proj(
    const float* __restrict__ x, const float* __restrict__ W,
    const float* __restrict__ a,
    u16* __restrict__ WxT,
    float* __restrict__ s_src,
    float* __restrict__ d_dst)
{
  const int b = blockIdx.x;
  const int h = b >> 7;
  const int i0 = (b & 127) * 32;
  const int t = threadIdx.x;
  const int lane = t & 63;
  const int rg = t >> 6;

  __shared__ float xT[32][34];
  __shared__ float Wl[32][64];

  float acc[8];
#pragma unroll
  for (int r = 0; r < 8; ++r) acc[r] = 0.f;

  for (int k0 = 0; k0 < IN_DIM; k0 += 32) {
    __syncthreads();
    {
      const int r = t >> 3;
      const int kg = t & 7;
      const float4 xv = *reinterpret_cast<const float4*>(
          x + (size_t)(i0 + r) * IN_DIM + k0 + kg * 4);
      xT[kg * 4 + 0][r] = xv.x;
      xT[kg * 4 + 1][r] = xv.y;
      xT[kg * 4 + 2][r] = xv.z;
      xT[kg * 4 + 3][r] = xv.w;
    }
    {
      const int kk0 = t >> 6;
#pragma unroll
      for (int i2 = 0; i2 < 8; ++i2) {
        const int kk = kk0 * 8 + i2;
        Wl[kk][lane] = W[((size_t)h * IN_DIM + k0 + kk) * HD + lane];
      }
    }
    __syncthreads();
#pragma unroll 4
    for (int kk = 0; kk < 32; ++kk) {
      const float w = Wl[kk][lane];
      const float2* xp = reinterpret_cast<const float2*>(&xT[kk][rg * 8]);
      const float2 x01 = xp[0], x23 = xp[1], x45 = xp[2], x67 = xp[3];
      acc[0] = fmaf(x01.x, w, acc[0]);
      acc[1] = fmaf(x01.y, w, acc[1]);
      acc[2] = fmaf(x23.x, w, acc[2]);
      acc[3] = fmaf(x23.y, w, acc[3]);
      acc[4] = fmaf(x45.x, w, acc[4]);
      acc[5] = fmaf(x45.y, w, acc[5]);
      acc[6] = fmaf(x67.x, w, acc[6]);
      acc[7] = fmaf(x67.y, w, acc[7]);
    }
  }

  const float asw = a[(size_t)h * 2 * HD + lane];
  const float adw = a[(size_t)h * 2 * HD + HD + lane];

  u16 us[8];
#pragma unroll
  for (int r = 0; r < 8; ++r) {
    __hip_bfloat16 bv = __float2bfloat16(acc[r]);
    us[r] = *reinterpret_cast<const u16*>(&bv);
  }
  uint4 pk;
  pk.x = (u32)us[0] | ((u32)us[1] << 16);
  pk.y = (u32)us[2] | ((u32)us[3] << 16);
  pk.z = (u32)us[4] | ((u32)us[5] << 16);
  pk.w = (u32)us[6] | ((u32)us[7] << 16);
  *reinterpret_cast<uint4*>(WxT + (size_t)(h * HD + lane) * NN + i0 + rg * 8) = pk;

#pragma unroll
  for (int r = 0; r < 8; ++r) {
    float sv = acc[r] * asw;
    float dv = acc[r] * adw;
#pragma unroll
    for (int mm = 32; mm >= 1; mm >>= 1) {
      sv += __shfl_xor(sv, mm);
      dv += __shfl_xor(dv, mm);
    }
    if (lane == 0) {
      const int i = i0 + rg * 8 + r;
      s_src[(size_t)h * NN + i] = sv * LOG2E;   // log2 domain
      d_dst[(size_t)h * NN + i] = dv * LOG2E;   // log2 domain
    }
  }
}

// ---------------------------------------------------------------------------
// K2: maxd[h] = max_j d_dst[h][j] (log2 domain)
// ---------------------------------------------------------------------------
__global__ __launch_bounds__(1024) void k2_maxd(
    const float* __restrict__ d_dst, float* __restrict__ maxd)
{
  __shared__ float red[16];
  const int h = blockIdx.x;
  const int t = threadIdx.x;
  float mx = -3.4e38f;
  for (int idx = t; idx < NN; idx += 1024)
    mx = fmaxf(mx, d_dst[(size_t)h * NN + idx]);
#pragma unroll
  for (int mm = 32; mm >= 1; mm >>= 1) mx = fmaxf(mx, __shfl_xor(mx, mm));
  if ((t & 63) == 0) red[t >> 6] = mx;
  __syncthreads();
  if (t == 0) {
    float m2 = red[0];
#pragma unroll
    for (int q = 1; q < 16; ++q) m2 = fmaxf(m2, red[q]);
    maxd[h] = m2;
  }
}

// ---------------------------------------------------------------------------
// K3: masked rank-1 softmax + PV, LDS-staged & double-buffered.
// grid (16 i-blocks, 4 heads, 4 j-quarters), block 512 = 8 waves.
// Wave wv owns rows [bx*256 + wv*32, +32) (two 16-row A-frag sets), head
// blockIdx.y, j in [jq*1024, +1024) as 8 tiles of 128 (4 K-steps each).
// WxT tile [64][128] staged reg->LDS with XOR-swizzle (row&7 on 16B units);
// mask staged to padded LDS; d broadcast from L2. Row-sums via ones-B MFMA.
// Partials (bf16) + sums -> ws; merged in K4 (upper-bound stabilizer =>
// partials merge by plain addition).
// ---------------------------------------------------------------------------
__global__ __launch_bounds__(512) void k3_attn(
    const u8* __restrict__ mask,
    const u16* __restrict__ WxT,
    const float* __restrict__ s_src, const float* __restrict__ d_dst,
    const float* __restrict__ maxd,
    u16* __restrict__ Pp, float* __restrict__ Sp)
{
  const int bx = blockIdx.x;
  const int h = blockIdx.y;
  const int jq = blockIdx.z;
  const int t = threadIdx.x;
  const int wv = t >> 6;
  const int lane = t & 63;
  const int rloc = lane & 15;
  const int g = lane >> 4;
  const int i_base = bx * 256 + wv * 32;

  __shared__ u16 wt[2][64 * 128];   // [buf][row*128 + unit*8], XOR-swizzled
  __shared__ u32 mk[256 * 36];      // [row][36 words] (32 used, pad 4)

  // ---- per-row softmax constants (log2 domain, upper-bound stabilizer) ----
  const float md = maxd[h];
  const float si0 = s_src[(size_t)h * NN + i_base + rloc];
  const float si1 = s_src[(size_t)h * NN + i_base + 16 + rloc];
  const float e00 = si0 + md, e01 = si1 + md;
  const float m0 = fmaxf(e00, NEG_SLOPE * e00);
  const float m1 = fmaxf(e01, NEG_SLOPE * e01);
  const float sa0 = si0 - m0, sb0 = fmaf(NEG_SLOPE, si0, -m0);
  const float sa1 = si1 - m1, sb1 = fmaf(NEG_SLOPE, si1, -m1);

  const float* dg = d_dst + (size_t)h * NN + jq * 1024;
  const u16* wsrc = WxT + (size_t)(h * HD) * NN + jq * 1024;

  // ---- staging thread mapping ----
  const int r0 = t >> 4;       // rows r0 and r0+32
  const int un = t & 15;       // 16B unit within row
  const int up = un ^ (r0 & 7);  // swizzled dest unit (same for r0+32)

  // ---- prologue: mask (once) + WxT tile 0 ----
#pragma unroll
  for (int k = 0; k < 4; ++k) {
    const int n = k * 512 + t;
    const int row = n >> 3;
    const int quad = n & 7;
    const uint4 mv = *reinterpret_cast<const uint4*>(
        mask + ((size_t)(bx * 256 + row) * (NN / 8)) + jq * 128 + quad * 16);
    *reinterpret_cast<uint4*>(&mk[row * 36 + quad * 4]) = mv;
  }
  {
    const uint4 s0 = *reinterpret_cast<const uint4*>(wsrc + (size_t)r0 * NN + un * 8);
    const uint4 s1 = *reinterpret_cast<const uint4*>(wsrc + (size_t)(r0 + 32) * NN + un * 8);
    *reinterpret_cast<uint4*>(&wt[0][r0 * 128 + up * 8]) = s0;
    *reinterpret_cast<uint4*>(&wt[0][(r0 + 32) * 128 + up * 8]) = s1;
  }
  __syncthreads();

  f32x4 acc0[4] = {}, acc1[4] = {};
  f32x4 accs0 = {}, accs1 = {};
  short8 ones;
#pragma unroll
  for (int e = 0; e < 8; ++e) ones[e] = (short)0x3F80;   // bf16 1.0

  int buf = 0;
  for (int tile = 0; tile < 8; ++tile) {
    // --- issue next tile's global loads (T14: early issue, late ds_write) ---
    uint4 n0, n1;
    const bool pf = (tile < 7);
    if (pf) {
      n0 = *reinterpret_cast<const uint4*>(
          wsrc + (size_t)r0 * NN + (tile + 1) * 128 + un * 8);
      n1 = *reinterpret_cast<const uint4*>(
          wsrc + (size_t)(r0 + 32) * NN + (tile + 1) * 128 + un * 8);
    }

    // --- compute current tile ---
    const uint4 mq0 = *reinterpret_cast<const uint4*>(
        &mk[(wv * 32 + rloc) * 36 + tile * 4]);
    const uint4 mq1 = *reinterpret_cast<const uint4*>(
        &mk[(wv * 32 + 16 + rloc) * 36 + tile * 4]);
#pragma unroll
    for (int ks = 0; ks < 4; ++ks) {
      short8 bfr[4];
#pragma unroll
      for (int dt = 0; dt < 4; ++dt) {
        const int row = dt * 16 + rloc;
        const int unit = (ks * 4 + g) ^ (row & 7);
        bfr[dt] = *reinterpret_cast<const short8*>(&wt[buf][row * 128 + unit * 8]);
      }
      const int jloc = tile * 128 + ks * 32 + g * 8;
      const float4 d0 = *reinterpret_cast<const float4*>(dg + jloc);
      const float4 d1 = *reinterpret_cast<const float4*>(dg + jloc + 4);
      const float dvv[8] = {d0.x, d0.y, d0.z, d0.w, d1.x, d1.y, d1.z, d1.w};
      const u32 mw0 = (ks == 0) ? mq0.x : (ks == 1) ? mq0.y : (ks == 2) ? mq0.z : mq0.w;
      const u32 mw1 = (ks == 0) ? mq1.x : (ks == 1) ? mq1.y : (ks == 2) ? mq1.z : mq1.w;
      const u32 mb0 = (mw0 >> (g * 8)) & 0xffu;
      const u32 mb1 = (mw1 >> (g * 8)) & 0xffu;
      short8 af0, af1;
#pragma unroll
      for (int e = 0; e < 8; ++e) {
        const float dj = dvv[e];
        float x0 = fmaxf(sa0 + dj, fmaf(NEG_SLOPE, dj, sb0));
        float x1 = fmaxf(sa1 + dj, fmaf(NEG_SLOPE, dj, sb1));
        x0 = (mb0 & (1u << e)) ? x0 : -400.f;
        x1 = (mb1 & (1u << e)) ? x1 : -400.f;
        float p0, p1;
        asm("v_exp_f32 %0, %1" : "=v"(p0) : "v"(x0));   // 2^x
        asm("v_exp_f32 %0, %1" : "=v"(p1) : "v"(x1));
        __hip_bfloat16 b0 = __float2bfloat16(p0);
        __hip_bfloat16 b1 = __float2bfloat16(p1);
        af0[e] = *reinterpret_cast<const short*>(&b0);
        af1[e] = *reinterpret_cast<const short*>(&b1);
      }
#pragma unroll
      for (int dt = 0; dt < 4; ++dt) {
        acc0[dt] = __builtin_amdgcn_mfma_f32_16x16x32_bf16(af0, bfr[dt], acc0[dt], 0, 0, 0);
        acc1[dt] = __builtin_amdgcn_mfma_f32_16x16x32_bf16(af1, bfr[dt], acc1[dt], 0, 0, 0);
      }
      accs0 = __builtin_amdgcn_mfma_f32_16x16x32_bf16(af0, ones, accs0, 0, 0, 0);
      accs1 = __builtin_amdgcn_mfma_f32_16x16x32_bf16(af1, ones, accs1, 0, 0, 0);
    }

    // --- late ds_write of the prefetched tile, then barrier ---
    if (pf) {
      *reinterpret_cast<uint4*>(&wt[buf ^ 1][r0 * 128 + up * 8]) = n0;
      *reinterpret_cast<uint4*>(&wt[buf ^ 1][(r0 + 32) * 128 + up * 8]) = n1;
    }
    __syncthreads();
    buf ^= 1;
  }

  // ---- epilogue: bf16 partial tiles + row sums ----
  u16* Pb = Pp + (size_t)jq * NN * OUT_DIM;
#pragma unroll
  for (int dt = 0; dt < 4; ++dt)
#pragma unroll
    for (int q = 0; q < 4; ++q) {
      __hip_bfloat16 v0 = __float2bfloat16(acc0[dt][q]);
      __hip_bfloat16 v1 = __float2bfloat16(acc1[dt][q]);
      Pb[(size_t)(i_base + g * 4 + q) * OUT_DIM + h * HD + dt * 16 + rloc] =
          *reinterpret_cast<const u16*>(&v0);
      Pb[(size_t)(i_base + 16 + g * 4 + q) * OUT_DIM + h * HD + dt * 16 + rloc] =
          *reinterpret_cast<const u16*>(&v1);
    }
  if (rloc == 0) {
    *reinterpret_cast<f32x4*>(&Sp[((size_t)jq * NH + h) * NN + i_base + g * 4]) = accs0;
    *reinterpret_cast<f32x4*>(&Sp[((size_t)jq * NH + h) * NN + i_base + 16 + g * 4]) = accs1;
  }
}

// ---------------------------------------------------------------------------
// K4: merge 4 j-quarter partials, normalize, ELU, LayerNorm, store.
// grid 256 (16 rows/block), block 256 = 4 waves; wave = 4 rows; lane = 4 cols.
// ---------------------------------------------------------------------------
__global__ __launch_bounds__(256) void k4_final(
    const u16* __restrict__ Pp, const float* __restrict__ Sp,
    const float* __restrict__ gamma, const float* __restrict__ beta,
    float* __restrict__ out)
{
  const int i0 = blockIdx.x * 16;
  const int t = threadIdx.x;
  const int wv = t >> 6;
  const int lane = t & 63;
  const int c0 = lane * 4;
  const int h = lane >> 4;

  const float4 gm = *reinterpret_cast<const float4*>(gamma + c0);
  const float4 bt = *reinterpret_cast<const float4*>(beta + c0);

  for (int rr = 0; rr < 4; ++rr) {
    const int i = i0 + wv * 4 + rr;
    float v[4] = {0.f, 0.f, 0.f, 0.f};
    float denom = 0.f;
#pragma unroll
    for (int q = 0; q < 4; ++q) {
      const ushort4 pv = *reinterpret_cast<const ushort4*>(
          Pp + (size_t)q * NN * OUT_DIM + (size_t)i * OUT_DIM + c0);
      v[0] += __uint_as_float((u32)pv.x << 16);
      v[1] += __uint_as_float((u32)pv.y << 16);
      v[2] += __uint_as_float((u32)pv.z << 16);
      v[3] += __uint_as_float((u32)pv.w << 16);
      denom += Sp[((size_t)q * NH + h) * NN + i];
    }
    const float inv = 1.f / denom;
    float sum = 0.f, sq = 0.f;
#pragma unroll
    for (int q2 = 0; q2 < 4; ++q2) {
      float x = v[q2] * inv;
      x = (x > 0.f) ? x : expm1f(x);
      v[q2] = x;
      sum += x;
      sq += x * x;
    }
#pragma unroll
    for (int mm = 32; mm >= 1; mm >>= 1) {
      sum += __shfl_xor(sum, mm);
      sq += __shfl_xor(sq, mm);
    }
    const float mu = sum * (1.f / OUT_DIM);
    const float var = sq * (1.f / OUT_DIM) - mu * mu;
    const float rs = rsqrtf(var + LN_EPS);
    float4 o;
    o.x = (v[0] - mu) * rs * gm.x + bt.x;
    o.y = (v[1] - mu) * rs * gm.y + bt.y;
    o.z = (v[2] - mu) * rs * gm.z + bt.z;
    o.w = (v[3] - mu) * rs * gm.w + bt.w;
    *reinterpret_cast<float4*>(out + (size_t)i * OUT_DIM + c0) = o;
  }
}

extern "C" void kernel_launch(void* const* d_in, const int* in_sizes, int n_in,
                              void* d_out, int out_size, void* d_ws, size_t ws_size,
                              hipStream_t stream) {
  const float* x = (const float*)d_in[0];
  const int* adj = (const int*)d_in[1];
  const float* W = (const float*)d_in[2];
  const float* a = (const float*)d_in[3];
  const float* gamma = (const float*)d_in[4];
  const float* beta = (const float*)d_in[5];
  float* out = (float*)d_out;

  char* ws = (char*)d_ws;
  size_t off = 0;
  u16* WxT = (u16*)(ws + off);        off += (size_t)NH * HD * NN * 2;          // 2 MiB
  float* s_src = (float*)(ws + off);  off += (size_t)NH * NN * 4;               // 64 KiB
  float* d_dst = (float*)(ws + off);  off += (size_t)NH * NN * 4;               // 64 KiB
  float* maxd = (float*)(ws + off);   off += 256;
  u8* mask = (u8*)(ws + off);         off += (size_t)NN * (NN / 8);             // 2 MiB
  u16* Pp = (u16*)(ws + off);         off += (size_t)4 * NN * OUT_DIM * 2;      // 8 MiB (bf16)
  float* Sp = (float*)(ws + off);     off += (size_t)4 * NH * NN * 4;           // 256 KiB

  k0_pack<<<dim3(512), dim3(1024), 0, stream>>>(adj, mask);
  k1_proj<<<dim3(512), dim3(256), 0, stream>>>(x, W, a, WxT, s_src, d_dst);
  k2_maxd<<<dim3(NH), dim3(1024), 0, stream>>>(d_dst, maxd);
  k3_attn<<<dim3(16, NH, 4), dim3(512), 0, stream>>>(mask, WxT, s_src, d_dst,
                                                     maxd, Pp, Sp);
  k4_final<<<dim3(256), dim3(256), 0, stream>>>(Pp, Sp, gamma, beta, out);
}

// Round 7
// 66.446 us; speedup vs baseline: 2.2640x; 1.3306x over previous
//
#include <hip/hip_runtime.h>
#include <hip/hip_bf16.h>

#define NN 4096
#define IN_DIM 512
#define OUT_DIM 256
#define NH 4
#define HD 64
#define NEG_SLOPE 0.2f
#define LN_EPS 1e-5f
#define LOG2E 1.4426950408889634f

typedef __attribute__((ext_vector_type(8))) short short8;
typedef __attribute__((ext_vector_type(4))) float f32x4;
typedef unsigned short u16;
typedef unsigned int u32;
typedef unsigned long long u64;
typedef unsigned char u8;

// ---------------------------------------------------------------------------
// K0: pack (adj>0)|I into bitmask [NN][NN/8 B]; blocks < 128 also transpose
// W [H][K][D] f32 -> Wt [h*64+d][512] bf16 (one element per thread).
// ---------------------------------------------------------------------------
__global__ __launch_bounds__(1024) void k0_pack(
    const int* __restrict__ adj, u8* __restrict__ mask,
    const float* __restrict__ W, u16* __restrict__ Wt)
{
  const int b = blockIdx.x;
  const int t = threadIdx.x;
#pragma unroll
  for (int it = 0; it < 4; ++it) {
    const int row = b * 8 + it * 2 + (t >> 9);
    const int byte = t & 511;
    const int j0 = byte * 8;
    const int4 v0 = *reinterpret_cast<const int4*>(adj + (size_t)row * NN + j0);
    const int4 v1 = *reinterpret_cast<const int4*>(adj + (size_t)row * NN + j0 + 4);
    const int vv[8] = {v0.x, v0.y, v0.z, v0.w, v1.x, v1.y, v1.z, v1.w};
    u32 bbits = 0;
#pragma unroll
    for (int c = 0; c < 8; ++c)
      if ((vv[c] > 0) || (row == j0 + c)) bbits |= (1u << c);
    mask[(size_t)row * (NN / 8) + byte] = (u8)bbits;
  }
  if (b < 128) {
    // n = h*2^15 + k*2^6 + d  (exactly the flat index of W)
    const int n = b * 1024 + t;
    const int d = n & 63;
    const int k = (n >> 6) & 511;
    const int h = n >> 15;
    __hip_bfloat16 bv = __float2bfloat16(W[n]);
    Wt[(size_t)(h * HD + d) * IN_DIM + k] = *reinterpret_cast<const u16*>(&bv);
  }
}

// ---------------------------------------------------------------------------
// K1: MFMA projection. grid 256 (16-row tiles), block 256 = 4 waves (wave=head).
// Stage x[i0..i0+16][512] as bf16 in LDS (XOR-swizzled 16B units), 1 barrier,
// then 16 K-steps: 1 A ds_read_b128 + 4 B 16B loads (L2-resident Wt) + 4 MFMA.
// Epilogue: WxT bf16 [h*64+d][NN] written directly (ushort4), s/d scores via
// per-lane dot + 4-step shfl reduce, stored ×LOG2E.
// ---------------------------------------------------------------------------
__global__ __launch_bounds__(256, 4) void k1_proj(
    const float* __restrict__ x, const u16* __restrict__ Wt,
    const float* __restrict__ a,
    u16* __restrict__ WxT,
    float* __restrict__ s_src,
    float* __restrict__ d_dst)
{
  const int i0 = blockIdx.x * 16;
  const int t = threadIdx.x;
  const int h = t >> 6;          // wave = head
  const int lane = t & 63;
  const int rloc = lane & 15;
  const int g = lane >> 4;

  __shared__ u16 xl[16 * 512];   // [row][unit*8], units XOR-swizzled by row&7

  // ---- stage x tile: thread t -> row t>>4, units (t&15)*4 .. +3 ----
  {
    const int r = t >> 4;
    const int ug = t & 15;
    const float* xr = x + (size_t)(i0 + r) * IN_DIM + ug * 32;
#pragma unroll
    for (int jj = 0; jj < 4; ++jj) {
      const float4 lo = *reinterpret_cast<const float4*>(xr + jj * 8);
      const float4 hi = *reinterpret_cast<const float4*>(xr + jj * 8 + 4);
      const float fv[8] = {lo.x, lo.y, lo.z, lo.w, hi.x, hi.y, hi.z, hi.w};
      u16 us[8];
#pragma unroll
      for (int e = 0; e < 8; ++e) {
        __hip_bfloat16 bv = __float2bfloat16(fv[e]);
        us[e] = *reinterpret_cast<const u16*>(&bv);
      }
      const int u = ug * 4 + jj;
      const int phys = (u & 56) | ((u & 7) ^ (r & 7));
      uint4 pk;
      pk.x = (u32)us[0] | ((u32)us[1] << 16);
      pk.y = (u32)us[2] | ((u32)us[3] << 16);
      pk.z = (u32)us[4] | ((u32)us[5] << 16);
      pk.w = (u32)us[6] | ((u32)us[7] << 16);
      *reinterpret_cast<uint4*>(&xl[r * 512 + phys * 8]) = pk;
    }
  }
  __syncthreads();

  // ---- MFMA main loop ----
  f32x4 acc[4] = {};
  const u16* wb = Wt + (size_t)(h * HD + rloc) * IN_DIM;
#pragma unroll
  for (int ks = 0; ks < 16; ++ks) {
    const int u = ks * 4 + g;
    const int phys = (u & 56) | ((u & 7) ^ (rloc & 7));
    const short8 af = *reinterpret_cast<const short8*>(&xl[rloc * 512 + phys * 8]);
#pragma unroll
    for (int dt = 0; dt < 4; ++dt) {
      const short8 bf = *reinterpret_cast<const short8*>(
          wb + (size_t)dt * 16 * IN_DIM + ks * 32 + g * 8);
      acc[dt] = __builtin_amdgcn_mfma_f32_16x16x32_bf16(af, bf, acc[dt], 0, 0, 0);
    }
  }

  // ---- epilogue: direct WxT store + scores ----
  // acc[dt][q] = C[i = g*4+q][d = dt*16 + rloc]
#pragma unroll
  for (int dt = 0; dt < 4; ++dt) {
    u16 us[4];
#pragma unroll
    for (int q = 0; q < 4; ++q) {
      __hip_bfloat16 bv = __float2bfloat16(acc[dt][q]);
      us[q] = *reinterpret_cast<const u16*>(&bv);
    }
    ushort4 pk = {us[0], us[1], us[2], us[3]};
    *reinterpret_cast<ushort4*>(
        WxT + (size_t)(h * HD + dt * 16 + rloc) * NN + i0 + g * 4) = pk;
  }

  float as_v[4], ad_v[4];
#pragma unroll
  for (int dt = 0; dt < 4; ++dt) {
    as_v[dt] = a[(size_t)h * 2 * HD + dt * 16 + rloc];
    ad_v[dt] = a[(size_t)h * 2 * HD + HD + dt * 16 + rloc];
  }
  float sv[4], dv[4];
#pragma unroll
  for (int q = 0; q < 4; ++q) {
    float s = 0.f, d = 0.f;
#pragma unroll
    for (int dt = 0; dt < 4; ++dt) {
      s = fmaf(acc[dt][q], as_v[dt], s);
      d = fmaf(acc[dt][q], ad_v[dt], d);
    }
    sv[q] = s; dv[q] = d;
  }
#pragma unroll
  for (int mm = 8; mm >= 1; mm >>= 1) {
#pragma unroll
    for (int q = 0; q < 4; ++q) {
      sv[q] += __shfl_xor(sv[q], mm);
      dv[q] += __shfl_xor(dv[q], mm);
    }
  }
  if (rloc == 0) {
#pragma unroll
    for (int q = 0; q < 4; ++q) {
      const int i = i0 + g * 4 + q;
      s_src[(size_t)h * NN + i] = sv[q] * LOG2E;
      d_dst[(size_t)h * NN + i] = dv[q] * LOG2E;
    }
  }
}

// ---------------------------------------------------------------------------
// K2: maxd[h] = max_j d_dst[h][j] (log2 domain)
// ---------------------------------------------------------------------------
__global__ __launch_bounds__(1024) void k2_maxd(
    const float* __restrict__ d_dst, float* __restrict__ maxd)
{
  __shared__ float red[16];
  const int h = blockIdx.x;
  const int t = threadIdx.x;
  float mx = -3.4e38f;
  for (int idx = t; idx < NN; idx += 1024)
    mx = fmaxf(mx, d_dst[(size_t)h * NN + idx]);
#pragma unroll
  for (int mm = 32; mm >= 1; mm >>= 1) mx = fmaxf(mx, __shfl_xor(mx, mm));
  if ((t & 63) == 0) red[t >> 6] = mx;
  __syncthreads();
  if (t == 0) {
    float m2 = red[0];
#pragma unroll
    for (int q = 1; q < 16; ++q) m2 = fmaxf(m2, red[q]);
    maxd[h] = m2;
  }
}

// ---------------------------------------------------------------------------
// K3: masked rank-1 softmax + PV, LDS-staged & double-buffered (unchanged).
// grid (16 i-blocks, 4 heads, 4 j-quarters), block 512 = 8 waves.
// ---------------------------------------------------------------------------
__global__ __launch_bounds__(512) void k3_attn(
    const u8* __restrict__ mask,
    const u16* __restrict__ WxT,
    const float* __restrict__ s_src, const float* __restrict__ d_dst,
    const float* __restrict__ maxd,
    u16* __restrict__ Pp, float* __restrict__ Sp)
{
  const int bx = blockIdx.x;
  const int h = blockIdx.y;
  const int jq = blockIdx.z;
  const int t = threadIdx.x;
  const int wv = t >> 6;
  const int lane = t & 63;
  const int rloc = lane & 15;
  const int g = lane >> 4;
  const int i_base = bx * 256 + wv * 32;

  __shared__ u16 wt[2][64 * 128];
  __shared__ u32 mk[256 * 36];

  const float md = maxd[h];
  const float si0 = s_src[(size_t)h * NN + i_base + rloc];
  const float si1 = s_src[(size_t)h * NN + i_base + 16 + rloc];
  const float e00 = si0 + md, e01 = si1 + md;
  const float m0 = fmaxf(e00, NEG_SLOPE * e00);
  const float m1 = fmaxf(e01, NEG_SLOPE * e01);
  const float sa0 = si0 - m0, sb0 = fmaf(NEG_SLOPE, si0, -m0);
  const float sa1 = si1 - m1, sb1 = fmaf(NEG_SLOPE, si1, -m1);

  const float* dg = d_dst + (size_t)h * NN + jq * 1024;
  const u16* wsrc = WxT + (size_t)(h * HD) * NN + jq * 1024;

  const int r0 = t >> 4;
  const int un = t & 15;
  const int up = un ^ (r0 & 7);

#pragma unroll
  for (int k = 0; k < 4; ++k) {
    const int n = k * 512 + t;
    const int row = n >> 3;
    const int quad = n & 7;
    const uint4 mv = *reinterpret_cast<const uint4*>(
        mask + ((size_t)(bx * 256 + row) * (NN / 8)) + jq * 128 + quad * 16);
    *reinterpret_cast<uint4*>(&mk[row * 36 + quad * 4]) = mv;
  }
  {
    const uint4 s0 = *reinterpret_cast<const uint4*>(wsrc + (size_t)r0 * NN + un * 8);
    const uint4 s1 = *reinterpret_cast<const uint4*>(wsrc + (size_t)(r0 + 32) * NN + un * 8);
    *reinterpret_cast<uint4*>(&wt[0][r0 * 128 + up * 8]) = s0;
    *reinterpret_cast<uint4*>(&wt[0][(r0 + 32) * 128 + up * 8]) = s1;
  }
  __syncthreads();

  f32x4 acc0[4] = {}, acc1[4] = {};
  f32x4 accs0 = {}, accs1 = {};
  short8 ones;
#pragma unroll
  for (int e = 0; e < 8; ++e) ones[e] = (short)0x3F80;

  int buf = 0;
  for (int tile = 0; tile < 8; ++tile) {
    uint4 n0, n1;
    const bool pf = (tile < 7);
    if (pf) {
      n0 = *reinterpret_cast<const uint4*>(
          wsrc + (size_t)r0 * NN + (tile + 1) * 128 + un * 8);
      n1 = *reinterpret_cast<const uint4*>(
          wsrc + (size_t)(r0 + 32) * NN + (tile + 1) * 128 + un * 8);
    }

    const uint4 mq0 = *reinterpret_cast<const uint4*>(
        &mk[(wv * 32 + rloc) * 36 + tile * 4]);
    const uint4 mq1 = *reinterpret_cast<const uint4*>(
        &mk[(wv * 32 + 16 + rloc) * 36 + tile * 4]);
#pragma unroll
    for (int ks = 0; ks < 4; ++ks) {
      short8 bfr[4];
#pragma unroll
      for (int dt = 0; dt < 4; ++dt) {
        const int row = dt * 16 + rloc;
        const int unit = (ks * 4 + g) ^ (row & 7);
        bfr[dt] = *reinterpret_cast<const short8*>(&wt[buf][row * 128 + unit * 8]);
      }
      const int jloc = tile * 128 + ks * 32 + g * 8;
      const float4 d0 = *reinterpret_cast<const float4*>(dg + jloc);
      const float4 d1 = *reinterpret_cast<const float4*>(dg + jloc + 4);
      const float dvv[8] = {d0.x, d0.y, d0.z, d0.w, d1.x, d1.y, d1.z, d1.w};
      const u32 mw0 = (ks == 0) ? mq0.x : (ks == 1) ? mq0.y : (ks == 2) ? mq0.z : mq0.w;
      const u32 mw1 = (ks == 0) ? mq1.x : (ks == 1) ? mq1.y : (ks == 2) ? mq1.z : mq1.w;
      const u32 mb0 = (mw0 >> (g * 8)) & 0xffu;
      const u32 mb1 = (mw1 >> (g * 8)) & 0xffu;
      short8 af0, af1;
#pragma unroll
      for (int e = 0; e < 8; ++e) {
        const float dj = dvv[e];
        float x0 = fmaxf(sa0 + dj, fmaf(NEG_SLOPE, dj, sb0));
        float x1 = fmaxf(sa1 + dj, fmaf(NEG_SLOPE, dj, sb1));
        x0 = (mb0 & (1u << e)) ? x0 : -400.f;
        x1 = (mb1 & (1u << e)) ? x1 : -400.f;
        float p0, p1;
        asm("v_exp_f32 %0, %1" : "=v"(p0) : "v"(x0));
        asm("v_exp_f32 %0, %1" : "=v"(p1) : "v"(x1));
        __hip_bfloat16 b0 = __float2bfloat16(p0);
        __hip_bfloat16 b1 = __float2bfloat16(p1);
        af0[e] = *reinterpret_cast<const short*>(&b0);
        af1[e] = *reinterpret_cast<const short*>(&b1);
      }
#pragma unroll
      for (int dt = 0; dt < 4; ++dt) {
        acc0[dt] = __builtin_amdgcn_mfma_f32_16x16x32_bf16(af0, bfr[dt], acc0[dt], 0, 0, 0);
        acc1[dt] = __builtin_amdgcn_mfma_f32_16x16x32_bf16(af1, bfr[dt], acc1[dt], 0, 0, 0);
      }
      accs0 = __builtin_amdgcn_mfma_f32_16x16x32_bf16(af0, ones, accs0, 0, 0, 0);
      accs1 = __builtin_amdgcn_mfma_f32_16x16x32_bf16(af1, ones, accs1, 0, 0, 0);
    }

    if (pf) {
      *reinterpret_cast<uint4*>(&wt[buf ^ 1][r0 * 128 + up * 8]) = n0;
      *reinterpret_cast<uint4*>(&wt[buf ^ 1][(r0 + 32) * 128 + up * 8]) = n1;
    }
    __syncthreads();
    buf ^= 1;
  }

  u16* Pb = Pp + (size_t)jq * NN * OUT_DIM;
#pragma unroll
  for (int dt = 0; dt < 4; ++dt)
#pragma unroll
    for (int q = 0; q < 4; ++q) {
      __hip_bfloat16 v0 = __float2bfloat16(acc0[dt][q]);
      __hip_bfloat16 v1 = __float2bfloat16(acc1[dt][q]);
      Pb[(size_t)(i_base + g * 4 + q) * OUT_DIM + h * HD + dt * 16 + rloc] =
          *reinterpret_cast<const u16*>(&v0);
      Pb[(size_t)(i_base + 16 + g * 4 + q) * OUT_DIM + h * HD + dt * 16 + rloc] =
          *reinterpret_cast<const u16*>(&v1);
    }
  if (rloc == 0) {
    *reinterpret_cast<f32x4*>(&Sp[((size_t)jq * NH + h) * NN + i_base + g * 4]) = accs0;
    *reinterpret_cast<f32x4*>(&Sp[((size_t)jq * NH + h) * NN + i_base + 16 + g * 4]) = accs1;
  }
}

// ---------------------------------------------------------------------------
// K4: merge 4 j-quarter partials, normalize, ELU, LayerNorm, store (unchanged).
// ---------------------------------------------------------------------------
__global__ __launch_bounds__(256) void k4_final(
    const u16* __restrict__ Pp, const float* __restrict__ Sp,
    const float* __restrict__ gamma, const float* __restrict__ beta,
    float* __restrict__ out)
{
  const int i0 = blockIdx.x * 16;
  const int t = threadIdx.x;
  const int wv = t >> 6;
  const int lane = t & 63;
  const int c0 = lane * 4;
  const int h = lane >> 4;

  const float4 gm = *reinterpret_cast<const float4*>(gamma + c0);
  const float4 bt = *reinterpret_cast<const float4*>(beta + c0);

  for (int rr = 0; rr < 4; ++rr) {
    const int i = i0 + wv * 4 + rr;
    float v[4] = {0.f, 0.f, 0.f, 0.f};
    float denom = 0.f;
#pragma unroll
    for (int q = 0; q < 4; ++q) {
      const ushort4 pv = *reinterpret_cast<const ushort4*>(
          Pp + (size_t)q * NN * OUT_DIM + (size_t)i * OUT_DIM + c0);
      v[0] += __uint_as_float((u32)pv.x << 16);
      v[1] += __uint_as_float((u32)pv.y << 16);
      v[2] += __uint_as_float((u32)pv.z << 16);
      v[3] += __uint_as_float((u32)pv.w << 16);
      denom += Sp[((size_t)q * NH + h) * NN + i];
    }
    const float inv = 1.f / denom;
    float sum = 0.f, sq = 0.f;
#pragma unroll
    for (int q2 = 0; q2 < 4; ++q2) {
      float xx = v[q2] * inv;
      xx = (xx > 0.f) ? xx : expm1f(xx);
      v[q2] = xx;
      sum += xx;
      sq += xx * xx;
    }
#pragma unroll
    for (int mm = 32; mm >= 1; mm >>= 1) {
      sum += __shfl_xor(sum, mm);
      sq += __shfl_xor(sq, mm);
    }
    const float mu = sum * (1.f / OUT_DIM);
    const float var = sq * (1.f / OUT_DIM) - mu * mu;
    const float rs = rsqrtf(var + LN_EPS);
    float4 o;
    o.x = (v[0] - mu) * rs * gm.x + bt.x;
    o.y = (v[1] - mu) * rs * gm.y + bt.y;
    o.z = (v[2] - mu) * rs * gm.z + bt.z;
    o.w = (v[3] - mu) * rs * gm.w + bt.w;
    *reinterpret_cast<float4*>(out + (size_t)i * OUT_DIM + c0) = o;
  }
}

extern "C" void kernel_launch(void* const* d_in, const int* in_sizes, int n_in,
                              void* d_out, int out_size, void* d_ws, size_t ws_size,
                              hipStream_t stream) {
  const float* x = (const float*)d_in[0];
  const int* adj = (const int*)d_in[1];
  const float* W = (const float*)d_in[2];
  const float* a = (const float*)d_in[3];
  const float* gamma = (const float*)d_in[4];
  const float* beta = (const float*)d_in[5];
  float* out = (float*)d_out;

  char* ws = (char*)d_ws;
  size_t off = 0;
  u16* WxT = (u16*)(ws + off);        off += (size_t)NH * HD * NN * 2;          // 2 MiB
  float* s_src = (float*)(ws + off);  off += (size_t)NH * NN * 4;               // 64 KiB
  float* d_dst = (float*)(ws + off);  off += (size_t)NH * NN * 4;               // 64 KiB
  float* maxd = (float*)(ws + off);   off += 256;
  u8* mask = (u8*)(ws + off);         off += (size_t)NN * (NN / 8);             // 2 MiB
  u16* Pp = (u16*)(ws + off);         off += (size_t)4 * NN * OUT_DIM * 2;      // 8 MiB (bf16)
  float* Sp = (float*)(ws + off);     off += (size_t)4 * NH * NN * 4;           // 256 KiB
  u16* Wt = (u16*)(ws + off);         off += (size_t)NH * HD * IN_DIM * 2;      // 256 KiB

  k0_pack<<<dim3(512), dim3(1024), 0, stream>>>(adj, mask, W, Wt);
  k1_proj<<<dim3(256), dim3(256), 0, stream>>>(x, Wt, a, WxT, s_src, d_dst);
  k2_maxd<<<dim3(NH), dim3(1024), 0, stream>>>(d_dst, maxd);
  k3_attn<<<dim3(16, NH, 4), dim3(512), 0, stream>>>(mask, WxT, s_src, d_dst,
                                                     maxd, Pp, Sp);
  k4_final<<<dim3(256), dim3(256), 0, stream>>>(Pp, Sp, gamma, beta, out);
}